// Round 11
// baseline (485.034 us; speedup 1.0000x reference)
//
#include <hip/hip_runtime.h>

typedef unsigned short u16;
typedef unsigned int u32;
typedef __attribute__((ext_vector_type(8))) short bf16x8;
typedef __attribute__((ext_vector_type(4))) float f32x4;

#define MX_ 4096      // B*N1 rows of x-stream
#define NT_ 1152      // N1+N2 tokens
#define C_  1152
#define DP_ 96        // padded head dim (Q)
#define DPK_ 128      // padded head dim (K LDS-staging layout)
#define D_  72
#define H_  16
#define MT_ 4608      // total rows (x 4096 + c 512)

static __device__ __forceinline__ float b2f(u16 u){ union{u32 i; float f;} x; x.i=((u32)u)<<16; return x.f; }
static __device__ __forceinline__ u16 f2b(float f){ u32 i=__float_as_uint(f); return (u16)((i + 0x7FFFu + ((i>>16)&1u))>>16); }

static __device__ __forceinline__ void gl_lds16(const u16* g, u16* l){
  __builtin_amdgcn_global_load_lds((const __attribute__((address_space(1))) void*)g,
                                   (__attribute__((address_space(3))) void*)l, 16, 0, 0);
}

#define MFMA16(a,b,c) __builtin_amdgcn_mfma_f32_16x16x32_bf16(a,b,c,0,0,0)

// ---------------- transpose (K,N) fp32 -> (N,K) bf16 for all 8 weight matrices ----------------
struct TrArgs {
  const float* src[8]; u16* dst[8]; int K[8]; int N[8]; int start[9];
};

__global__ __launch_bounds__(256) void transpose_kernel(TrArgs a){
  int bx = blockIdx.x;
  int mi = 0;
  #pragma unroll
  for (int i = 0; i < 8; ++i) if (bx >= a.start[i+1]) mi = i+1;
  int t = bx - a.start[mi];
  int K = a.K[mi], N = a.N[mi];
  int ntk = K >> 5;
  int tk = t % ntk, tn = t / ntk;
  int k0 = tk*32, n0 = tn*32;
  __shared__ u16 lds[32][33];
  int c = threadIdx.x & 31, r = threadIdx.x >> 5;
  const float* src = a.src[mi];
  u16* dst = a.dst[mi];
  #pragma unroll
  for (int ii = 0; ii < 4; ++ii){
    int row = r + ii*8;
    lds[row][c] = f2b(src[(size_t)(k0+row)*N + n0 + c]);
  }
  __syncthreads();
  #pragma unroll
  for (int ii = 0; ii < 4; ++ii){
    int row = r + ii*8;
    dst[(size_t)(n0+row)*K + k0 + c] = lds[c][row];
  }
}

// ---------------- adaLN: s = silu(global_c); mod = s @ ada_w + ada_b (fp32 out) ----------------
__global__ __launch_bounds__(256) void ada_kernel(const float* gc, const float* wx, const float* bx,
                                                  const float* wc, const float* bc,
                                                  float* mod_x, float* mod_c){
  __shared__ float s[4][C_];
  __shared__ float part[4][4][64];
  int tid = threadIdx.x;
  for (int i = tid; i < 4*C_; i += 256){
    float v = gc[i];
    s[i / C_][i % C_] = v / (1.f + __expf(-v));
  }
  __syncthreads();
  int jq = tid & 63;
  int kq = tid >> 6;
  int jg = blockIdx.x*64 + jq;
  int which = jg / 6912;
  int j = jg % 6912;
  const float* W = which ? wc : wx;
  float a0=0.f, a1=0.f, a2=0.f, a3=0.f;
  for (int k = kq*288; k < kq*288 + 288; ++k){
    float w = W[(size_t)k*6912 + j];
    a0 += s[0][k]*w; a1 += s[1][k]*w; a2 += s[2][k]*w; a3 += s[3][k]*w;
  }
  part[kq][0][jq]=a0; part[kq][1][jq]=a1; part[kq][2][jq]=a2; part[kq][3][jq]=a3;
  __syncthreads();
  if (kq == 0){
    float bb = (which ? bc : bx)[j];
    float* out = which ? mod_c : mod_x;
    #pragma unroll
    for (int b = 0; b < 4; ++b){
      out[(size_t)b*6912 + j] = part[0][b][jq] + part[1][b][jq] + part[2][b][jq] + part[3][b][jq] + bb;
    }
  }
}

// ---------------- fused LayerNorm + modulate (fp32 in, bf16 out) ----------------
__global__ __launch_bounds__(256) void ln_mod_kernel(
  const float* srcx, const float* srcc, const float* g, const float* bt,
  const float* gcn, const float* btc,
  const float* shx, const float* scx, const float* shc, const float* scc,
  u16* out)
{
  int m = blockIdx.x;
  bool isC = (m >= MX_);
  const float* src = isC ? srcc + (size_t)(m - MX_)*C_ : srcx + (size_t)m*C_;
  int bidx = isC ? ((m - MX_) >> 7) : (m >> 10);
  const float* gg = isC ? gcn : g;
  const float* bb = isC ? btc : bt;
  const float* sh = (isC ? shc : shx) + (size_t)bidx*6912;
  const float* sc = (isC ? scc : scx) + (size_t)bidx*6912;
  int tid = threadIdx.x;
  float lv[8];
  float sum = 0.f, sq = 0.f;
  if (tid < 144){
    float4 v0 = *(const float4*)(src + tid*8);
    float4 v1 = *(const float4*)(src + tid*8 + 4);
    lv[0]=v0.x; lv[1]=v0.y; lv[2]=v0.z; lv[3]=v0.w;
    lv[4]=v1.x; lv[5]=v1.y; lv[6]=v1.z; lv[7]=v1.w;
    #pragma unroll
    for (int j = 0; j < 8; ++j){ sum += lv[j]; sq += lv[j]*lv[j]; }
  }
  #pragma unroll
  for (int off = 1; off < 64; off <<= 1){ sum += __shfl_xor(sum, off); sq += __shfl_xor(sq, off); }
  __shared__ float rs[4], rq[4];
  int wave = tid >> 6, lane = tid & 63;
  if (lane == 0){ rs[wave] = sum; rq[wave] = sq; }
  __syncthreads();
  float S = rs[0]+rs[1]+rs[2]+rs[3];
  float Q = rq[0]+rq[1]+rq[2]+rq[3];
  float mean = S * (1.f/1152.f);
  float var  = Q * (1.f/1152.f) - mean*mean;
  float rstd = rsqrtf(var + 1e-6f);
  if (tid < 144){
    union { uint4 v; u16 s[8]; } o;
    #pragma unroll
    for (int j = 0; j < 8; ++j){
      int n = tid*8 + j;
      float val = (lv[j] - mean)*rstd*gg[n] + bb[n];
      val = val*(1.f + sc[n]) + sh[n];
      o.s[j] = f2b(val);
    }
    *(uint4*)(out + (size_t)m*C_ + tid*8) = o.v;
  }
}

// ---------------- split-K reduce: out = resid + gate*(p0+p1+bias) ----------------
__global__ __launch_bounds__(256) void reduce2_kernel(
  const float* p,                       // [2][4608][1152] raw partial sums
  const float* residx, const float* residc,
  const float* modx, const float* modc,
  const float* biasx, const float* biasc,
  float* outx, float* outc)
{
  for (int i4 = blockIdx.x*256 + threadIdx.x; i4 < MT_*288; i4 += gridDim.x*256){
    int m = i4 / 288, n4 = (i4 % 288)*4;
    bool isC = (m >= MX_);
    int bidx = isC ? ((m - MX_) >> 7) : (m >> 10);
    const float* gate  = (isC ? modc : modx) + (size_t)bidx*6912;
    const float* bias  = isC ? biasc : biasx;
    const float* resid = isC ? residc + (size_t)(m - MX_)*C_ : residx + (size_t)m*C_;
    float* o = isC ? outc + (size_t)(m - MX_)*C_ : outx + (size_t)m*C_;
    float4 a = *(const float4*)(p + (size_t)m*C_ + n4);
    float4 b = *(const float4*)(p + (size_t)(MT_ + m)*C_ + n4);
    float4 r = *(const float4*)(resid + n4);
    float4 ov;
    ov.x = r.x + gate[n4+0]*(a.x + b.x + bias[n4+0]);
    ov.y = r.y + gate[n4+1]*(a.y + b.y + bias[n4+1]);
    ov.z = r.z + gate[n4+2]*(a.z + b.z + bias[n4+2]);
    ov.w = r.w + gate[n4+3]*(a.w + b.w + bias[n4+3]);
    *(float4*)(o + n4) = ov;
  }
}

// ---------------- GEMM: C = A @ B(^T stored), single-buffer 32KB, XCD-swizzled ----------------
// EPI 0: bias -> bf16; EPI 1: gelu(bias+acc) -> bf16; EPI 2: resid + gate*(acc+bias) -> f32
// EPI 3: raw acc -> f32 partial at outx + z*MT_*N (split-K; bias/resid/gate in reduce2)
struct GemmArgs {
  const u16* A; int lda; int rowmap;       // rowmap 1 = O-buffer token map
  const u16* BTx; const u16* BTc;          // [N][K] bf16 row-major (pre-transposed)
  const float* biasx; const float* biasc;
  void* outx; void* outc;
  const float* residx; const float* residc;
  const float* gatex; const float* gatec;  // + b*6912 applied inside
  int N, K, kLen;
};

static __device__ __forceinline__ int amap(int m, int rowmap){
  if (rowmap){
    if (m < MX_) return (m >> 10)*NT_ + (m & 1023);
    int mm = m - MX_;
    return (mm >> 7)*NT_ + 1024 + (mm & 127);
  }
  return m;
}

template<int EPI>
__global__ __launch_bounds__(256, 2) void gemm_kernel(GemmArgs g){
  __shared__ u16 As[128*64];
  __shared__ u16 Bs[128*64];
  // m204 bijective XCD-chunked swizzle: contiguous by-bands per XCD (A-band/XCD unique, B streams)
  int gx = gridDim.x, gy = gridDim.y;
  int nwg = gx*gy;
  int orig = blockIdx.y*gx + blockIdx.x;
  int q = nwg >> 3, r8 = nwg & 7;
  int xcd = orig & 7, wi = orig >> 3;
  int swz = (xcd < r8 ? xcd*(q+1) : r8*(q+1) + (xcd - r8)*q) + wi;
  int n0 = (swz % gx)*128, m0 = (swz / gx)*128;
  int kStart = blockIdx.z * g.kLen;
  bool isC = (m0 >= MX_);
  const u16* BT = isC ? g.BTc : g.BTx;
  int tid = threadIdx.x, wave = tid >> 6, lane = tid & 63;
  int lg = lane >> 4, lr = lane & 15;
  int wm = wave >> 1, wn = wave & 1;
  f32x4 acc[4][4] = {};

  // hoisted per-lane staging source addresses (k offset added per step)
  const u16* Aaddr[4]; const u16* Baddr[4];
  #pragma unroll
  for (int i = 0; i < 4; ++i){
    int cb = (wave*4 + i)*64;
    int qq = cb + lane;
    int row = qq >> 3;
    int c16 = (qq & 7) ^ (row & 7);           // XOR-swizzle: both-sides (source pre-swizzled)
    Aaddr[i] = g.A + (size_t)amap(m0 + row, g.rowmap)*g.lda + kStart + c16*8;
    Baddr[i] = BT + (size_t)(n0 + row)*g.K + kStart + c16*8;
  }
  for (int k0 = 0; k0 < g.kLen; k0 += 64){
    #pragma unroll
    for (int i = 0; i < 4; ++i){
      int cb = (wave*4 + i)*64;
      gl_lds16(Aaddr[i] + k0, As + cb*8);
      gl_lds16(Baddr[i] + k0, Bs + cb*8);
    }
    __syncthreads();
    #pragma unroll
    for (int kkI = 0; kkI < 2; ++kkI){
      bf16x8 af[4], bfr[4];
      #pragma unroll
      for (int mi = 0; mi < 4; ++mi){
        int row = wm*64 + mi*16 + lr;
        int c16 = (kkI*4 + lg) ^ (row & 7);
        af[mi] = *(const bf16x8*)&As[row*64 + c16*8];
      }
      #pragma unroll
      for (int ni = 0; ni < 4; ++ni){
        int row = wn*64 + ni*16 + lr;
        int c16 = (kkI*4 + lg) ^ (row & 7);
        bfr[ni] = *(const bf16x8*)&Bs[row*64 + c16*8];
      }
      #pragma unroll
      for (int mi = 0; mi < 4; ++mi)
        #pragma unroll
        for (int ni = 0; ni < 4; ++ni)
          acc[mi][ni] = MFMA16(af[mi], bfr[ni], acc[mi][ni]);
    }
    __syncthreads();
  }

  // epilogue
  const float* bias  = isC ? g.biasc : g.biasx;
  const float* resid = isC ? g.residc : g.residx;
  void* out = isC ? g.outc : g.outx;
  const float* gate = nullptr;
  if (EPI == 2){
    int bidx = isC ? ((m0 - MX_) >> 7) : (m0 >> 10);
    gate = (isC ? g.gatec : g.gatex) + (size_t)bidx*6912;
  }
  int mbase = isC ? (m0 - MX_) : m0;
  float* pbase = nullptr;
  if (EPI == 3) pbase = (float*)g.outx + (size_t)blockIdx.z*MT_*C_;
  #pragma unroll
  for (int mi = 0; mi < 4; ++mi){
    #pragma unroll
    for (int r = 0; r < 4; ++r){
      #pragma unroll
      for (int ni = 0; ni < 4; ++ni){
        int n = n0 + wn*64 + ni*16 + lr;
        if (EPI == 3){
          size_t prow = (size_t)(m0 + wm*64 + mi*16 + lg*4 + r);
          pbase[prow*(size_t)g.N + n] = acc[mi][ni][r];
        } else {
          size_t orow = (size_t)(mbase + wm*64 + mi*16 + lg*4 + r);
          float v = acc[mi][ni][r] + bias[n];
          if (EPI == 1){
            float u = 0.7978845608028654f*(v + 0.044715f*v*v*v);
            v = 0.5f*v*(1.f + tanhf(u));
          }
          if (EPI == 2){
            v = resid[orow*(size_t)g.N + n] + gate[n]*v;
            ((float*)out)[orow*(size_t)g.N + n] = v;
          } else {
            ((u16*)out)[orow*(size_t)g.N + n] = f2b(v);
          }
        }
      }
    }
  }
}

// ---------------- head split + RMS-norm(q,k) + pad + V transpose ----------------
// q scaled by ATTN_SCALE*log2(e) (softmax runs in exp2 domain); K written to DPK_=128-stride
// buffer (zero cols 72..127) for linear LDS staging; vT row 72 = 1.0 (ones-row), 73-79 = 0
__global__ __launch_bounds__(256) void rmshead_kernel(
  const u16* qkv, const float* gqx, const float* gkx, const float* gqc, const float* gkc,
  u16* qpad, u16* kpadp, u16* vT)
{
  int tt = blockIdx.x, h = blockIdx.y, b = blockIdx.z;
  int t0 = tt*64;
  bool isC = (t0 >= 1024);
  size_t rowbase = isC ? (size_t)(MX_ + b*128 + (t0 - 1024)) : (size_t)(b*1024 + t0);
  __shared__ u16 sq[2][64][72];
  __shared__ u16 sv[64][72];
  __shared__ float nf[2][64];
  int tid = threadIdx.x;
  for (int s = tid; s < 1728; s += 256){
    int which = s / 576, rem = s % 576;
    int t = rem / 9, ch = rem % 9;
    uint4 v = *(const uint4*)(qkv + (rowbase + t)*3456 + which*C_ + h*D_ + ch*8);
    u16* dst = (which < 2) ? &sq[which][t][ch*8] : &sv[t][ch*8];
    *(uint4*)dst = v;
  }
  __syncthreads();
  {
    int row = tid >> 1, half = tid & 1;
    int which = row >> 6, t = row & 63;
    float ss = 0.f;
    for (int d = half*36; d < half*36 + 36; ++d){
      float v = b2f(sq[which][t][d]); ss += v*v;
    }
    ss += __shfl_xor(ss, 1);
    if (half == 0){
      const float* gp = (which == 0) ? (isC ? gqc : gqx) : (isC ? gkc : gkx);
      float f = 33.9411254970f * gp[0] / fmaxf(sqrtf(ss), 1e-12f);
      if (which == 0) f *= 0.17002324581205f;   // ATTN_SCALE * log2(e) folded into q
      nf[which][t] = f;
    }
  }
  __syncthreads();
  // Q: 64 rows x 12 chunks, DP_=96 stride
  size_t obaseQ = ((size_t)(b*H_ + h)*NT_ + t0) * DP_;
  for (int s = tid; s < 768; s += 256){
    int t = s / 12, ch = s % 12;
    float f = nf[0][t];
    union { uint4 v; u16 e[8]; } o;
    #pragma unroll
    for (int j = 0; j < 8; ++j){
      int d = ch*8 + j;
      o.e[j] = (d < D_) ? f2b(b2f(sq[0][t][d]) * f) : (u16)0;
    }
    *(uint4*)(qpad + obaseQ + (size_t)t*DP_ + ch*8) = o.v;
  }
  // K: 64 rows x 16 chunks, DPK_=128 stride (chunks 9..15 zero)
  size_t obaseK = ((size_t)(b*H_ + h)*NT_ + t0) * DPK_;
  for (int s = tid; s < 1024; s += 256){
    int t = s >> 4, ch = s & 15;
    union { uint4 v; u16 e[8]; } o;
    if (ch < 9){
      float f = nf[1][t];
      #pragma unroll
      for (int j = 0; j < 8; ++j){
        int d = ch*8 + j;
        o.e[j] = (d < D_) ? f2b(b2f(sq[1][t][d]) * f) : (u16)0;
      }
    } else {
      o.v = make_uint4(0,0,0,0);
    }
    *(uint4*)(kpadp + obaseK + (size_t)t*DPK_ + ch*8) = o.v;
  }
  size_t vbase = (size_t)(b*H_ + h)*80*NT_;
  for (int s = tid; s < 576; s += 256){
    int d = s / 8, ch = s % 8;
    union { uint4 v; u16 e[8]; } o;
    #pragma unroll
    for (int j = 0; j < 8; ++j) o.e[j] = sv[ch*8 + j][d];
    *(uint4*)(vT + vbase + (size_t)d*NT_ + t0 + ch*8) = o.v;
  }
  // pad rows: d=72 -> 1.0 (ones row => PV accumulates row-sum l), d=73..79 -> 0
  for (int s = tid; s < 512; s += 256){
    int d = 72 + (s >> 6), t = s & 63;
    vT[vbase + (size_t)d*NT_ + t0 + t] = (d == 72) ? (u16)0x3F80 : (u16)0;
  }
}

// ---------------- attention: 8 waves x 16 q-rows, K via LDS (global_load_lds, shared 8x) ----------------
// Grid 576 XCD-chunked (as before). K tile [32][128]u16 staged linearly into LDS with
// chunk-XOR applied on the GLOBAL SOURCE (both-sides rule, G21) -> ds_read_b128 2-way (free).
// Double-buffered with the GEMM-proven vmcnt(0)+barrier loop. V direct-to-regs (L2-resident).
// Per-wave register demand ~110 (qf12+acc20+vf20+st8+kf24) -> fits; no load sinking.
__global__ __launch_bounds__(512) void attn_kernel(
  const u16* qpad, const u16* kpadp, const u16* vT, u16* O)
{
  __shared__ u16 Ks[2][32*DPK_];   // 2 x 8KB
  __shared__ u16 Ps[8][16][40];    // per-wave P, stride 40 u16
  int orig = blockIdx.x;
  int w = (orig & 7)*72 + (orig >> 3);
  int qtb = w % 9, hb = w / 9;
  int h = hb & 15, b = hb >> 4;
  int bh = b*H_ + h;
  int tid = threadIdx.x, wave = tid >> 6, lane = tid & 63;
  int lg = lane >> 4, lr = lane & 15;
  int q0 = qtb*128 + wave*16;

  const u16* qb = qpad + (size_t)bh*NT_*DP_;
  const u16* kb = kpadp + (size_t)bh*NT_*DPK_;
  const u16* vb = vT + (size_t)bh*80*NT_;

  // Q fragments (held whole kernel)
  bf16x8 qf[3];
  #pragma unroll
  for (int kk = 0; kk < 3; ++kk)
    qf[kk] = *(const bf16x8*)(qb + (size_t)(q0 + lr)*DP_ + kk*32 + lg*8);

  f32x4 acc[5] = {};
  float m0 = -1e30f;

  // staging geometry: wave stages its 1KB slice (rows wave*4 .. wave*4+3)
  int srow = wave*4 + (lane >> 4);            // 16 lanes per 256B row
  int schunk = (lane & 15) ^ (srow & 7);      // source chunk (inverse-swizzle)
  const u16* ksrc = kb + (size_t)srow*DPK_ + schunk*8;
  u16* kdst0 = &Ks[0][(wave*4)*DPK_];
  u16* kdst1 = &Ks[1][(wave*4)*DPK_];

  auto STAGEK = [&](int buf, int kvt){
    gl_lds16(ksrc + (size_t)kvt*32*DPK_, buf ? kdst1 : kdst0);
  };

  u16* prow = &Ps[wave][lr][0];
  bf16x8 vf[5];

  STAGEK(0, 0);
  asm volatile("s_waitcnt vmcnt(0)" ::: "memory");
  __syncthreads();

  for (int t = 0; t < 36; ++t){
    int buf = t & 1;
    // V(t) to regs (consumed after QK+softmax; L2-hit latency covered)
    #pragma unroll
    for (int dc = 0; dc < 5; ++dc)
      vf[dc] = *(const bf16x8*)(vb + (size_t)(dc*16 + lr)*NT_ + t*32 + lg*8);
    // stage next K tile (no VGPR cost; drained at tile-end barrier)
    if (t + 1 < 36) STAGEK(buf ^ 1, t + 1);

    // K fragments from LDS (swizzled read side)
    const u16* kbase = &Ks[buf][0];
    bf16x8 kf[2][3];
    #pragma unroll
    for (int kt = 0; kt < 2; ++kt)
      #pragma unroll
      for (int kk = 0; kk < 3; ++kk){
        int row = kt*16 + lr;
        int ch  = (kk*4 + lg) ^ (lr & 7);
        kf[kt][kk] = *(const bf16x8*)&kbase[row*DPK_ + ch*8];
      }

    f32x4 st[2] = {};
    __builtin_amdgcn_s_setprio(1);
    #pragma unroll
    for (int kk = 0; kk < 3; ++kk){
      st[0] = MFMA16(kf[0][kk], qf[kk], st[0]);
      st[1] = MFMA16(kf[1][kk], qf[kk], st[1]);
    }
    __builtin_amdgcn_s_setprio(0);

    // defer-max online softmax in exp2 domain (threshold 8*log2e)
    float pm0 = fmaxf(fmaxf(fmaxf(st[0][0], st[0][1]), fmaxf(st[0][2], st[0][3])),
                      fmaxf(fmaxf(st[1][0], st[1][1]), fmaxf(st[1][2], st[1][3])));
    if (!__all(pm0 - m0 <= 11.5415603f)){
      float r0 = fmaxf(pm0, __shfl_xor(pm0, 16)); r0 = fmaxf(r0, __shfl_xor(r0, 32));
      float n0 = fmaxf(m0, r0);
      float f0 = exp2f(m0 - n0);
      m0 = n0;
      #pragma unroll
      for (int dc = 0; dc < 5; ++dc)
        #pragma unroll
        for (int j = 0; j < 4; ++j) acc[dc][j] *= f0;
    }
    // P = exp2(s' - m') -> bf16 via v_cvt_pk (RNE) -> LDS (wave-private rows)
    #pragma unroll
    for (int kt = 0; kt < 2; ++kt){
      float e0 = exp2f(st[kt][0] - m0);
      float e1 = exp2f(st[kt][1] - m0);
      float e2 = exp2f(st[kt][2] - m0);
      float e3 = exp2f(st[kt][3] - m0);
      u32 lo, hi;
      asm("v_cvt_pk_bf16_f32 %0, %1, %2" : "=v"(lo) : "v"(e0), "v"(e1));
      asm("v_cvt_pk_bf16_f32 %0, %1, %2" : "=v"(hi) : "v"(e2), "v"(e3));
      uint2 pkd; pkd.x = lo; pkd.y = hi;
      *(uint2*)(prow + kt*16 + lg*4) = pkd;
    }
    // ORDER FENCE (rule #18): pin ds_writes above / ds_reads below, drain LDS writes
    asm volatile("s_waitcnt lgkmcnt(0)" ::: "memory");
    __builtin_amdgcn_sched_barrier(0);
    bf16x8 bp = *(const bf16x8*)(prow + lg*8);
    __builtin_amdgcn_s_setprio(1);
    #pragma unroll
    for (int dc = 0; dc < 5; ++dc)
      acc[dc] = MFMA16(vf[dc], bp, acc[dc]);
    __builtin_amdgcn_s_setprio(0);

    // tile end: staged K(t+1) landed; all waves done reading Ks[buf]
    asm volatile("s_waitcnt vmcnt(0)" ::: "memory");
    __syncthreads();
  }

  // l sits in acc[4][0] of lanes lg==2 (d=72 ones-row); broadcast & normalize
  float l0 = __shfl(acc[4][0], 32 + lr);
  float rl0 = 1.f / l0;
  #pragma unroll
  for (int dc = 0; dc < 5; ++dc){
    if (dc < 4 || lg < 2){
      union { uint2 v; u16 e[4]; } o;
      #pragma unroll
      for (int j = 0; j < 4; ++j) o.e[j] = f2b(acc[dc][j] * rl0);
      int tok = q0 + lr;
      *(uint2*)(O + ((size_t)b*NT_ + tok)*C_ + h*D_ + dc*16 + lg*4) = o.v;
    }
  }
}

// ---------------- host ----------------
extern "C" void kernel_launch(void* const* d_in, const int* in_sizes, int n_in,
                              void* d_out, int out_size, void* d_ws, size_t ws_size,
                              hipStream_t stream)
{
  (void)in_sizes; (void)n_in; (void)out_size; (void)ws_size;
  const float* x        = (const float*)d_in[0];
  const float* c        = (const float*)d_in[1];
  const float* gc       = (const float*)d_in[2];
  const float* ada_x_w  = (const float*)d_in[3];
  const float* ada_x_b  = (const float*)d_in[4];
  const float* ada_c_w  = (const float*)d_in[5];
  const float* ada_c_b  = (const float*)d_in[6];
  const float* g1x_g    = (const float*)d_in[7];
  const float* g1x_b    = (const float*)d_in[8];
  const float* g2x_g    = (const float*)d_in[9];
  const float* g2x_b    = (const float*)d_in[10];
  const float* g1c_g    = (const float*)d_in[11];
  const float* g1c_b    = (const float*)d_in[12];
  const float* g2c_g    = (const float*)d_in[13];
  const float* g2c_b    = (const float*)d_in[14];
  const float* qkv_x_w  = (const float*)d_in[15];
  const float* qkv_x_b  = (const float*)d_in[16];
  const float* proj_x_w = (const float*)d_in[17];
  const float* proj_x_b = (const float*)d_in[18];
  const float* qkv_c_w  = (const float*)d_in[19];
  const float* qkv_c_b  = (const float*)d_in[20];
  const float* proj_c_w = (const float*)d_in[21];
  const float* proj_c_b = (const float*)d_in[22];
  const float* gq_x     = (const float*)d_in[23];
  const float* gk_x     = (const float*)d_in[24];
  const float* gq_c     = (const float*)d_in[25];
  const float* gk_c     = (const float*)d_in[26];
  const float* m_x_w1   = (const float*)d_in[27];
  const float* m_x_b1   = (const float*)d_in[28];
  const float* m_x_w2   = (const float*)d_in[29];
  const float* m_x_b2   = (const float*)d_in[30];
  const float* m_c_w1   = (const float*)d_in[31];
  const float* m_c_b1   = (const float*)d_in[32];
  const float* m_c_w2   = (const float*)d_in[33];
  const float* m_c_b2   = (const float*)d_in[34];
  float* out = (float*)d_out;

  char* ws = (char*)d_ws;
  size_t off = 0;
  auto alloc = [&](size_t bytes)->void*{ void* p = ws + off; off += (bytes + 255) & ~(size_t)255; return p; };
  u16* WTqx  = (u16*)alloc((size_t)3456*1152*2);
  u16* WTqc  = (u16*)alloc((size_t)3456*1152*2);
  u16* WTpx  = (u16*)alloc((size_t)1152*1152*2);
  u16* WTpc  = (u16*)alloc((size_t)1152*1152*2);
  u16* WTm1x = (u16*)alloc((size_t)4608*1152*2);
  u16* WTm2x = (u16*)alloc((size_t)1152*4608*2);
  u16* WTm1c = (u16*)alloc((size_t)4608*1152*2);
  u16* WTm2c = (u16*)alloc((size_t)1152*4608*2);
  float* mod_x = (float*)alloc((size_t)4*6912*4);
  float* mod_c = (float*)alloc((size_t)4*6912*4);
  u16* xin  = (u16*)alloc((size_t)4608*1152*2);
  u16* pool = (u16*)alloc((size_t)4608*4608*2);     // qkv out, later MLP hidden
  u16* qpad = (u16*)alloc((size_t)64*1152*96*2 + 4096);
  u16* kpadp= (u16*)alloc((size_t)64*1152*128*2 + 4096);
  u16* vTb  = (u16*)alloc((size_t)64*80*1152*2 + 4096);
  u16* Obuf = (u16*)alloc((size_t)4*1152*1152*2);
  float* x1c1 = (float*)alloc((size_t)4608*1152*4);
  // fc2 split-K partials reuse the dead qpad..Obuf span (55.4 MB >= 42.5 MB needed)
  float* fc2p = (float*)qpad;

  // L0: weight transposes (fp32 -> bf16 [N][K])
  {
    TrArgs ta;
    const float* srcs[8] = {qkv_x_w, qkv_c_w, proj_x_w, proj_c_w, m_x_w1, m_x_w2, m_c_w1, m_c_w2};
    u16* dsts[8]         = {WTqx, WTqc, WTpx, WTpc, WTm1x, WTm2x, WTm1c, WTm2c};
    int Ks[8] = {1152,1152,1152,1152,1152,4608,1152,4608};
    int Ns[8] = {3456,3456,1152,1152,4608,1152,4608,1152};
    int st = 0;
    for (int i = 0; i < 8; ++i){
      ta.src[i] = srcs[i]; ta.dst[i] = dsts[i]; ta.K[i] = Ks[i]; ta.N[i] = Ns[i];
      ta.start[i] = st; st += (Ks[i]/32)*(Ns[i]/32);
    }
    ta.start[8] = st;
    transpose_kernel<<<dim3(st), dim3(256), 0, stream>>>(ta);
  }
  // L1: adaLN modulation vectors
  ada_kernel<<<dim3(216), dim3(256), 0, stream>>>(gc, ada_x_w, ada_x_b, ada_c_w, ada_c_b, mod_x, mod_c);
  // L2: LN1 + modulate
  ln_mod_kernel<<<dim3(4608), dim3(256), 0, stream>>>(
      x, c, g1x_g, g1x_b, g1c_g, g1c_b,
      mod_x + 0, mod_x + 1152, mod_c + 0, mod_c + 1152, xin);
  // L3: qkv GEMM (merged x|c)
  {
    GemmArgs ga{};
    ga.A = xin; ga.lda = 1152; ga.rowmap = 0;
    ga.BTx = WTqx; ga.BTc = WTqc; ga.biasx = qkv_x_b; ga.biasc = qkv_c_b;
    ga.outx = pool; ga.outc = pool + (size_t)4096*3456;
    ga.N = 3456; ga.K = 1152; ga.kLen = 1152;
    gemm_kernel<0><<<dim3(27,36), dim3(256), 0, stream>>>(ga);
  }
  // L4: head split + RMS + pad + V^T (+ones row, q pre-scaled incl. log2e, K 128-stride)
  rmshead_kernel<<<dim3(18,16,4), dim3(256), 0, stream>>>(pool, gq_x, gk_x, gq_c, gk_c, qpad, kpadp, vTb);
  // L5: attention (XCD-chunked, 8 waves x 16 q-rows, K via LDS)
  attn_kernel<<<dim3(576), dim3(512), 0, stream>>>(qpad, kpadp, vTb, Obuf);
  // L6: proj + gated residual -> x1c1 (fp32), direct
  {
    GemmArgs ga{};
    ga.A = Obuf; ga.lda = 1152; ga.rowmap = 1;
    ga.BTx = WTpx; ga.BTc = WTpc; ga.biasx = proj_x_b; ga.biasc = proj_c_b;
    ga.outx = x1c1; ga.outc = x1c1 + (size_t)4096*1152;
    ga.residx = x; ga.residc = c;
    ga.gatex = mod_x + 2*1152; ga.gatec = mod_c + 2*1152;
    ga.N = 1152; ga.K = 1152; ga.kLen = 1152;
    gemm_kernel<2><<<dim3(9,36), dim3(256), 0, stream>>>(ga);
  }
  // L7: LN2 + modulate (reads fp32 x1c1)
  ln_mod_kernel<<<dim3(4608), dim3(256), 0, stream>>>(
      x1c1, x1c1 + (size_t)4096*1152, g2x_g, g2x_b, g2c_g, g2c_b,
      mod_x + 3*1152, mod_x + 4*1152, mod_c + 3*1152, mod_c + 4*1152, xin);
  // L8: MLP fc1 + GELU
  {
    GemmArgs ga{};
    ga.A = xin; ga.lda = 1152; ga.rowmap = 0;
    ga.BTx = WTm1x; ga.BTc = WTm1c; ga.biasx = m_x_b1; ga.biasc = m_c_b1;
    ga.outx = pool; ga.outc = pool + (size_t)4096*4608;
    ga.N = 4608; ga.K = 1152; ga.kLen = 1152;
    gemm_kernel<1><<<dim3(36,36), dim3(256), 0, stream>>>(ga);
  }
  // L9a: MLP fc2 split-K=2 -> raw fp32 partials (no atomics)
  {
    GemmArgs ga{};
    ga.A = pool; ga.lda = 4608; ga.rowmap = 0;
    ga.BTx = WTm2x; ga.BTc = WTm2c;
    ga.outx = fc2p;
    ga.N = 1152; ga.K = 4608; ga.kLen = 2304;
    gemm_kernel<3><<<dim3(9,36,2), dim3(256), 0, stream>>>(ga);
  }
  // L9b: reduce partials + bias + gate + residual -> d_out
  reduce2_kernel<<<dim3(2048), dim3(256), 0, stream>>>(
      fc2p, x1c1, x1c1 + (size_t)4096*1152,
      mod_x + 5*1152, mod_c + 5*1152, m_x_b2, m_c_b2,
      out, out + (size_t)4096*1152);
}

// Round 12
// 447.881 us; speedup vs baseline: 1.0830x; 1.0830x over previous
//
#include <hip/hip_runtime.h>

typedef unsigned short u16;
typedef unsigned int u32;
typedef __attribute__((ext_vector_type(8))) short bf16x8;
typedef __attribute__((ext_vector_type(4))) float f32x4;

#define MX_ 4096      // B*N1 rows of x-stream
#define NT_ 1152      // N1+N2 tokens
#define C_  1152
#define DP_ 96        // padded head dim for QK contraction
#define D_  72
#define H_  16
#define MT_ 4608      // total rows (x 4096 + c 512)

static __device__ __forceinline__ float b2f(u16 u){ union{u32 i; float f;} x; x.i=((u32)u)<<16; return x.f; }
static __device__ __forceinline__ u16 f2b(float f){ u32 i=__float_as_uint(f); return (u16)((i + 0x7FFFu + ((i>>16)&1u))>>16); }

static __device__ __forceinline__ void gl_lds16(const u16* g, u16* l){
  __builtin_amdgcn_global_load_lds((const __attribute__((address_space(1))) void*)g,
                                   (__attribute__((address_space(3))) void*)l, 16, 0, 0);
}

#define MFMA16(a,b,c) __builtin_amdgcn_mfma_f32_16x16x32_bf16(a,b,c,0,0,0)

// ---------------- transpose (K,N) fp32 -> (N,K) bf16; vectorized uint2 writes ----------------
struct TrArgs {
  const float* src[8]; u16* dst[8]; int K[8]; int N[8]; int start[9];
};

__global__ __launch_bounds__(256) void transpose_kernel(TrArgs a){
  int bx = blockIdx.x;
  int mi = 0;
  #pragma unroll
  for (int i = 0; i < 8; ++i) if (bx >= a.start[i+1]) mi = i+1;
  int t = bx - a.start[mi];
  int K = a.K[mi], N = a.N[mi];
  int ntk = K >> 5;
  int tk = t % ntk, tn = t / ntk;
  int k0 = tk*32, n0 = tn*32;
  __shared__ u16 lds[32][33];
  int c = threadIdx.x & 31, r = threadIdx.x >> 5;
  const float* src = a.src[mi];
  u16* dst = a.dst[mi];
  #pragma unroll
  for (int ii = 0; ii < 4; ++ii){
    int row = r + ii*8;
    lds[row][c] = f2b(src[(size_t)(k0+row)*N + n0 + c]);
  }
  __syncthreads();
  // write phase: 32 n-rows x 8 k-groups; each lane stores 4 u16 = uint2 (256B/wave coalesced)
  {
    int n = threadIdx.x >> 3, kg = threadIdx.x & 7;
    union { uint2 v; u16 e[4]; } o;
    #pragma unroll
    for (int j = 0; j < 4; ++j) o.e[j] = lds[kg*4 + j][n];
    *(uint2*)(dst + (size_t)(n0+n)*K + k0 + kg*4) = o.v;
  }
}

// ---------------- adaLN: s = silu(global_c); mod = s @ ada_w + ada_b (fp32 out) ----------------
__global__ __launch_bounds__(256) void ada_kernel(const float* gc, const float* wx, const float* bx,
                                                  const float* wc, const float* bc,
                                                  float* mod_x, float* mod_c){
  __shared__ float s[4][C_];
  __shared__ float part[4][4][64];
  int tid = threadIdx.x;
  for (int i = tid; i < 4*C_; i += 256){
    float v = gc[i];
    s[i / C_][i % C_] = v / (1.f + __expf(-v));
  }
  __syncthreads();
  int jq = tid & 63;
  int kq = tid >> 6;
  int jg = blockIdx.x*64 + jq;
  int which = jg / 6912;
  int j = jg % 6912;
  const float* W = which ? wc : wx;
  float a0=0.f, a1=0.f, a2=0.f, a3=0.f;
  for (int k = kq*288; k < kq*288 + 288; ++k){
    float w = W[(size_t)k*6912 + j];
    a0 += s[0][k]*w; a1 += s[1][k]*w; a2 += s[2][k]*w; a3 += s[3][k]*w;
  }
  part[kq][0][jq]=a0; part[kq][1][jq]=a1; part[kq][2][jq]=a2; part[kq][3][jq]=a3;
  __syncthreads();
  if (kq == 0){
    float bb = (which ? bc : bx)[j];
    float* out = which ? mod_c : mod_x;
    #pragma unroll
    for (int b = 0; b < 4; ++b){
      out[(size_t)b*6912 + j] = part[0][b][jq] + part[1][b][jq] + part[2][b][jq] + part[3][b][jq] + bb;
    }
  }
}

// ---------------- fused LayerNorm + modulate (fp32 in, bf16 out) ----------------
__global__ __launch_bounds__(256) void ln_mod_kernel(
  const float* srcx, const float* srcc, const float* g, const float* bt,
  const float* gcn, const float* btc,
  const float* shx, const float* scx, const float* shc, const float* scc,
  u16* out)
{
  int m = blockIdx.x;
  bool isC = (m >= MX_);
  const float* src = isC ? srcc + (size_t)(m - MX_)*C_ : srcx + (size_t)m*C_;
  int bidx = isC ? ((m - MX_) >> 7) : (m >> 10);
  const float* gg = isC ? gcn : g;
  const float* bb = isC ? btc : bt;
  const float* sh = (isC ? shc : shx) + (size_t)bidx*6912;
  const float* sc = (isC ? scc : scx) + (size_t)bidx*6912;
  int tid = threadIdx.x;
  float lv[8];
  float sum = 0.f, sq = 0.f;
  if (tid < 144){
    float4 v0 = *(const float4*)(src + tid*8);
    float4 v1 = *(const float4*)(src + tid*8 + 4);
    lv[0]=v0.x; lv[1]=v0.y; lv[2]=v0.z; lv[3]=v0.w;
    lv[4]=v1.x; lv[5]=v1.y; lv[6]=v1.z; lv[7]=v1.w;
    #pragma unroll
    for (int j = 0; j < 8; ++j){ sum += lv[j]; sq += lv[j]*lv[j]; }
  }
  #pragma unroll
  for (int off = 1; off < 64; off <<= 1){ sum += __shfl_xor(sum, off); sq += __shfl_xor(sq, off); }
  __shared__ float rs[4], rq[4];
  int wave = tid >> 6, lane = tid & 63;
  if (lane == 0){ rs[wave] = sum; rq[wave] = sq; }
  __syncthreads();
  float S = rs[0]+rs[1]+rs[2]+rs[3];
  float Q = rq[0]+rq[1]+rq[2]+rq[3];
  float mean = S * (1.f/1152.f);
  float var  = Q * (1.f/1152.f) - mean*mean;
  float rstd = rsqrtf(var + 1e-6f);
  if (tid < 144){
    union { uint4 v; u16 s[8]; } o;
    #pragma unroll
    for (int j = 0; j < 8; ++j){
      int n = tid*8 + j;
      float val = (lv[j] - mean)*rstd*gg[n] + bb[n];
      val = val*(1.f + sc[n]) + sh[n];
      o.s[j] = f2b(val);
    }
    *(uint4*)(out + (size_t)m*C_ + tid*8) = o.v;
  }
}

// ---------------- split-K reduce: out = resid + gate*(p0+p1+bias) ----------------
// p0, p1 are separate [4608][1152] raw partial buffers (p1 may alias out: read-before-write per elem)
__global__ __launch_bounds__(256) void reduce2_kernel(
  const float* p0, const float* p1,
  const float* residx, const float* residc,
  const float* modx, const float* modc,
  const float* biasx, const float* biasc,
  float* outx, float* outc)
{
  for (int i4 = blockIdx.x*256 + threadIdx.x; i4 < MT_*288; i4 += gridDim.x*256){
    int m = i4 / 288, n4 = (i4 % 288)*4;
    bool isC = (m >= MX_);
    int bidx = isC ? ((m - MX_) >> 7) : (m >> 10);
    const float* gate  = (isC ? modc : modx) + (size_t)bidx*6912;
    const float* bias  = isC ? biasc : biasx;
    const float* resid = isC ? residc + (size_t)(m - MX_)*C_ : residx + (size_t)m*C_;
    float* o = isC ? outc + (size_t)(m - MX_)*C_ : outx + (size_t)m*C_;
    float4 a = *(const float4*)(p0 + (size_t)m*C_ + n4);
    float4 b = *(const float4*)(p1 + (size_t)m*C_ + n4);
    float4 r = *(const float4*)(resid + n4);
    float4 ov;
    ov.x = r.x + gate[n4+0]*(a.x + b.x + bias[n4+0]);
    ov.y = r.y + gate[n4+1]*(a.y + b.y + bias[n4+1]);
    ov.z = r.z + gate[n4+2]*(a.z + b.z + bias[n4+2]);
    ov.w = r.w + gate[n4+3]*(a.w + b.w + bias[n4+3]);
    *(float4*)(o + n4) = ov;
  }
}

// ---------------- GEMM: C = A @ B(^T stored), single-buffer 32KB, XCD-swizzled ----------------
// EPI 0: bias -> bf16; EPI 1: gelu(bias+acc) -> bf16; EPI 2: resid + gate*(acc+bias) -> f32
// EPI 3: raw acc -> f32 partial (z=0 -> outx, z=1 -> outc; bias/resid/gate in reduce2)
struct GemmArgs {
  const u16* A; int lda; int rowmap;       // rowmap 1 = O-buffer token map
  const u16* BTx; const u16* BTc;          // [N][K] bf16 row-major (pre-transposed)
  const float* biasx; const float* biasc;
  void* outx; void* outc;
  const float* residx; const float* residc;
  const float* gatex; const float* gatec;  // + b*6912 applied inside
  int N, K, kLen;
};

static __device__ __forceinline__ int amap(int m, int rowmap){
  if (rowmap){
    if (m < MX_) return (m >> 10)*NT_ + (m & 1023);
    int mm = m - MX_;
    return (mm >> 7)*NT_ + 1024 + (mm & 127);
  }
  return m;
}

template<int EPI>
__global__ __launch_bounds__(256, 2) void gemm_kernel(GemmArgs g){
  __shared__ u16 As[128*64];
  __shared__ u16 Bs[128*64];
  // m204 bijective XCD-chunked swizzle: contiguous by-bands per XCD (A-band/XCD unique, B streams)
  int gx = gridDim.x, gy = gridDim.y;
  int nwg = gx*gy;
  int orig = blockIdx.y*gx + blockIdx.x;
  int q = nwg >> 3, r8 = nwg & 7;
  int xcd = orig & 7, wi = orig >> 3;
  int swz = (xcd < r8 ? xcd*(q+1) : r8*(q+1) + (xcd - r8)*q) + wi;
  int n0 = (swz % gx)*128, m0 = (swz / gx)*128;
  int kStart = blockIdx.z * g.kLen;
  bool isC = (m0 >= MX_);
  const u16* BT = isC ? g.BTc : g.BTx;
  int tid = threadIdx.x, wave = tid >> 6, lane = tid & 63;
  int lg = lane >> 4, lr = lane & 15;
  int wm = wave >> 1, wn = wave & 1;
  f32x4 acc[4][4] = {};

  // hoisted per-lane staging source addresses (k offset added per step)
  const u16* Aaddr[4]; const u16* Baddr[4];
  #pragma unroll
  for (int i = 0; i < 4; ++i){
    int cb = (wave*4 + i)*64;
    int qq = cb + lane;
    int row = qq >> 3;
    int c16 = (qq & 7) ^ (row & 7);           // XOR-swizzle: both-sides (source pre-swizzled)
    Aaddr[i] = g.A + (size_t)amap(m0 + row, g.rowmap)*g.lda + kStart + c16*8;
    Baddr[i] = BT + (size_t)(n0 + row)*g.K + kStart + c16*8;
  }
  for (int k0 = 0; k0 < g.kLen; k0 += 64){
    #pragma unroll
    for (int i = 0; i < 4; ++i){
      int cb = (wave*4 + i)*64;
      gl_lds16(Aaddr[i] + k0, As + cb*8);
      gl_lds16(Baddr[i] + k0, Bs + cb*8);
    }
    __syncthreads();
    #pragma unroll
    for (int kkI = 0; kkI < 2; ++kkI){
      bf16x8 af[4], bfr[4];
      #pragma unroll
      for (int mi = 0; mi < 4; ++mi){
        int row = wm*64 + mi*16 + lr;
        int c16 = (kkI*4 + lg) ^ (row & 7);
        af[mi] = *(const bf16x8*)&As[row*64 + c16*8];
      }
      #pragma unroll
      for (int ni = 0; ni < 4; ++ni){
        int row = wn*64 + ni*16 + lr;
        int c16 = (kkI*4 + lg) ^ (row & 7);
        bfr[ni] = *(const bf16x8*)&Bs[row*64 + c16*8];
      }
      #pragma unroll
      for (int mi = 0; mi < 4; ++mi)
        #pragma unroll
        for (int ni = 0; ni < 4; ++ni)
          acc[mi][ni] = MFMA16(af[mi], bfr[ni], acc[mi][ni]);
    }
    __syncthreads();
  }

  // epilogue
  const float* bias  = isC ? g.biasc : g.biasx;
  const float* resid = isC ? g.residc : g.residx;
  void* out = isC ? g.outc : g.outx;
  const float* gate = nullptr;
  if (EPI == 2){
    int bidx = isC ? ((m0 - MX_) >> 7) : (m0 >> 10);
    gate = (isC ? g.gatec : g.gatex) + (size_t)bidx*6912;
  }
  int mbase = isC ? (m0 - MX_) : m0;
  float* pbase = nullptr;
  if (EPI == 3) pbase = blockIdx.z ? (float*)g.outc : (float*)g.outx;
  #pragma unroll
  for (int mi = 0; mi < 4; ++mi){
    #pragma unroll
    for (int r = 0; r < 4; ++r){
      #pragma unroll
      for (int ni = 0; ni < 4; ++ni){
        int n = n0 + wn*64 + ni*16 + lr;
        if (EPI == 3){
          size_t prow = (size_t)(m0 + wm*64 + mi*16 + lg*4 + r);
          pbase[prow*(size_t)g.N + n] = acc[mi][ni][r];
        } else {
          size_t orow = (size_t)(mbase + wm*64 + mi*16 + lg*4 + r);
          float v = acc[mi][ni][r] + bias[n];
          if (EPI == 1){
            float u = 0.7978845608028654f*(v + 0.044715f*v*v*v);
            v = 0.5f*v*(1.f + tanhf(u));
          }
          if (EPI == 2){
            v = resid[orow*(size_t)g.N + n] + gate[n]*v;
            ((float*)out)[orow*(size_t)g.N + n] = v;
          } else {
            ((u16*)out)[orow*(size_t)g.N + n] = f2b(v);
          }
        }
      }
    }
  }
}

// ---------------- head split + RMS-norm(q,k) + pad + V transpose (R10 version) ----------------
// q scaled by ATTN_SCALE*log2(e) (softmax runs in exp2 domain); vT row 72 = 1.0 (ones-row
// accumulates l alongside O with identical rescaling), rows 73-79 = 0
__global__ __launch_bounds__(256) void rmshead_kernel(
  const u16* qkv, const float* gqx, const float* gkx, const float* gqc, const float* gkc,
  u16* qpad, u16* kpad, u16* vT)
{
  int tt = blockIdx.x, h = blockIdx.y, b = blockIdx.z;
  int t0 = tt*64;
  bool isC = (t0 >= 1024);
  size_t rowbase = isC ? (size_t)(MX_ + b*128 + (t0 - 1024)) : (size_t)(b*1024 + t0);
  __shared__ u16 sq[2][64][72];
  __shared__ u16 sv[64][72];
  __shared__ float nf[2][64];
  int tid = threadIdx.x;
  for (int s = tid; s < 1728; s += 256){
    int which = s / 576, rem = s % 576;
    int t = rem / 9, ch = rem % 9;
    uint4 v = *(const uint4*)(qkv + (rowbase + t)*3456 + which*C_ + h*D_ + ch*8);
    u16* dst = (which < 2) ? &sq[which][t][ch*8] : &sv[t][ch*8];
    *(uint4*)dst = v;
  }
  __syncthreads();
  {
    int row = tid >> 1, half = tid & 1;
    int which = row >> 6, t = row & 63;
    float ss = 0.f;
    for (int d = half*36; d < half*36 + 36; ++d){
      float v = b2f(sq[which][t][d]); ss += v*v;
    }
    ss += __shfl_xor(ss, 1);
    if (half == 0){
      const float* gp = (which == 0) ? (isC ? gqc : gqx) : (isC ? gkc : gkx);
      float f = 33.9411254970f * gp[0] / fmaxf(sqrtf(ss), 1e-12f);
      if (which == 0) f *= 0.17002324581205f;   // ATTN_SCALE * log2(e) folded into q
      nf[which][t] = f;
    }
  }
  __syncthreads();
  size_t obase = ((size_t)(b*H_ + h)*NT_ + t0) * DP_;
  for (int s = tid; s < 1536; s += 256){
    int which = s / 768, rem = s % 768;
    int t = rem / 12, ch = rem % 12;
    float f = nf[which][t];
    union { uint4 v; u16 e[8]; } o;
    #pragma unroll
    for (int j = 0; j < 8; ++j){
      int d = ch*8 + j;
      o.e[j] = (d < D_) ? f2b(b2f(sq[which][t][d]) * f) : (u16)0;
    }
    *(uint4*)((which == 0 ? qpad : kpad) + obase + (size_t)t*DP_ + ch*8) = o.v;
  }
  size_t vbase = (size_t)(b*H_ + h)*80*NT_;
  for (int s = tid; s < 576; s += 256){
    int d = s / 8, ch = s % 8;
    union { uint4 v; u16 e[8]; } o;
    #pragma unroll
    for (int j = 0; j < 8; ++j) o.e[j] = sv[ch*8 + j][d];
    *(uint4*)(vT + vbase + (size_t)d*NT_ + t0 + ch*8) = o.v;
  }
  // pad rows: d=72 -> 1.0 (ones row => PV accumulates row-sum l), d=73..79 -> 0
  for (int s = tid; s < 512; s += 256){
    int d = 72 + (s >> 6), t = s & 63;
    vT[vbase + (size_t)d*NT_ + t0 + t] = (d == 72) ? (u16)0x3F80 : (u16)0;
  }
}

// ---------------- attention: 32 q-rows/wave, XCD-chunked, barrier-free (R10 exact) ----------------
__global__ __launch_bounds__(256) void attn_kernel(
  const u16* qpad, const u16* kpad, const u16* vT, u16* O)
{
  __shared__ u16 Ps[4][32][40];     // per-wave P, stride 40 u16 (5x16B, odd => conflict-free b128)
  int orig = blockIdx.x;
  int w = (orig & 7)*72 + (orig >> 3);
  int qtb = w % 9, hb = w / 9;
  int h = hb & 15, b = hb >> 4;
  int bh = b*H_ + h;
  int tid = threadIdx.x, wave = tid >> 6, lane = tid & 63;
  int lg = lane >> 4, lr = lane & 15;
  int q0 = qtb*128 + wave*32;

  const u16* qb = qpad + (size_t)bh*NT_*DP_;
  const u16* kb = kpad + (size_t)bh*NT_*DP_;
  const u16* vb = vT + (size_t)bh*80*NT_;

  bf16x8 qf[2][3];
  #pragma unroll
  for (int qt = 0; qt < 2; ++qt)
    #pragma unroll
    for (int kk = 0; kk < 3; ++kk)
      qf[qt][kk] = *(const bf16x8*)(qb + (size_t)(q0 + qt*16 + lr)*DP_ + kk*32 + lg*8);

  f32x4 acc[5][2] = {};
  float m0 = -1e30f, m1 = -1e30f;

  bf16x8 kfA[2][3], kfB[2][3], vf[5];
  auto LOADK = [&](bf16x8 (&kf)[2][3], int kvt){
    #pragma unroll
    for (int kt = 0; kt < 2; ++kt)
      #pragma unroll
      for (int kk = 0; kk < 3; ++kk)
        kf[kt][kk] = *(const bf16x8*)(kb + (size_t)(kvt*32 + kt*16 + lr)*DP_ + kk*32 + lg*8);
  };
  u16* prow0 = &Ps[wave][lr][0];
  u16* prow1 = &Ps[wave][16 + lr][0];

  auto TILE = [&](bf16x8 (&kf)[2][3], bf16x8 (&kfn)[2][3], int t){
    #pragma unroll
    for (int dc = 0; dc < 5; ++dc)
      vf[dc] = *(const bf16x8*)(vb + (size_t)(dc*16 + lr)*NT_ + t*32 + lg*8);
    if (t + 1 < 36) LOADK(kfn, t + 1);

    f32x4 st[2][2] = {};
    __builtin_amdgcn_s_setprio(1);
    #pragma unroll
    for (int kk = 0; kk < 3; ++kk){
      st[0][0] = MFMA16(kf[0][kk], qf[0][kk], st[0][0]);
      st[0][1] = MFMA16(kf[0][kk], qf[1][kk], st[0][1]);
      st[1][0] = MFMA16(kf[1][kk], qf[0][kk], st[1][0]);
      st[1][1] = MFMA16(kf[1][kk], qf[1][kk], st[1][1]);
    }
    __builtin_amdgcn_s_setprio(0);

    // defer-max online softmax in exp2 domain (threshold 8*log2e)
    float pm0 = fmaxf(fmaxf(fmaxf(st[0][0][0], st[0][0][1]), fmaxf(st[0][0][2], st[0][0][3])),
                      fmaxf(fmaxf(st[1][0][0], st[1][0][1]), fmaxf(st[1][0][2], st[1][0][3])));
    float pm1 = fmaxf(fmaxf(fmaxf(st[0][1][0], st[0][1][1]), fmaxf(st[0][1][2], st[0][1][3])),
                      fmaxf(fmaxf(st[1][1][0], st[1][1][1]), fmaxf(st[1][1][2], st[1][1][3])));
    float tt = fmaxf(pm0 - m0, pm1 - m1);
    if (!__all(tt <= 11.5415603f)){
      float r0 = fmaxf(pm0, __shfl_xor(pm0, 16)); r0 = fmaxf(r0, __shfl_xor(r0, 32));
      float r1 = fmaxf(pm1, __shfl_xor(pm1, 16)); r1 = fmaxf(r1, __shfl_xor(r1, 32));
      float n0 = fmaxf(m0, r0), n1 = fmaxf(m1, r1);
      float f0 = exp2f(m0 - n0), f1 = exp2f(m1 - n1);
      m0 = n0; m1 = n1;
      #pragma unroll
      for (int dc = 0; dc < 5; ++dc)
        #pragma unroll
        for (int j = 0; j < 4; ++j){ acc[dc][0][j] *= f0; acc[dc][1][j] *= f1; }
    }
    // P = exp2(s' - m') -> bf16 via v_cvt_pk (RNE) -> LDS (wave-private rows)
    #pragma unroll
    for (int kt = 0; kt < 2; ++kt){
      #pragma unroll
      for (int qt = 0; qt < 2; ++qt){
        float mm = qt ? m1 : m0;
        float e0 = exp2f(st[kt][qt][0] - mm);
        float e1 = exp2f(st[kt][qt][1] - mm);
        float e2 = exp2f(st[kt][qt][2] - mm);
        float e3 = exp2f(st[kt][qt][3] - mm);
        u32 lo, hi;
        asm("v_cvt_pk_bf16_f32 %0, %1, %2" : "=v"(lo) : "v"(e0), "v"(e1));
        asm("v_cvt_pk_bf16_f32 %0, %1, %2" : "=v"(hi) : "v"(e2), "v"(e3));
        uint2 pkd; pkd.x = lo; pkd.y = hi;
        *(uint2*)((qt ? prow1 : prow0) + kt*16 + lg*4) = pkd;
      }
    }
    // ORDER FENCE (rule #18): pin ds_writes above / ds_reads below, drain LDS writes
    asm volatile("s_waitcnt lgkmcnt(0)" ::: "memory");
    __builtin_amdgcn_sched_barrier(0);
    bf16x8 bp0 = *(const bf16x8*)(prow0 + lg*8);
    bf16x8 bp1 = *(const bf16x8*)(prow1 + lg*8);
    __builtin_amdgcn_s_setprio(1);
    #pragma unroll
    for (int dc = 0; dc < 5; ++dc){
      acc[dc][0] = MFMA16(vf[dc], bp0, acc[dc][0]);
      acc[dc][1] = MFMA16(vf[dc], bp1, acc[dc][1]);
    }
    __builtin_amdgcn_s_setprio(0);
  };

  LOADK(kfA, 0);
  for (int t2 = 0; t2 < 18; ++t2){
    TILE(kfA, kfB, 2*t2);
    TILE(kfB, kfA, 2*t2 + 1);
  }

  float l0 = __shfl(acc[4][0][0], 32 + lr);
  float l1 = __shfl(acc[4][1][0], 32 + lr);
  float rl0 = 1.f / l0, rl1 = 1.f / l1;
  #pragma unroll
  for (int dc = 0; dc < 5; ++dc){
    #pragma unroll
    for (int qt = 0; qt < 2; ++qt){
      if (dc < 4 || lg < 2){
        float rl = qt ? rl1 : rl0;
        union { uint2 v; u16 e[4]; } o;
        #pragma unroll
        for (int j = 0; j < 4; ++j) o.e[j] = f2b(acc[dc][qt][j] * rl);
        int tok = q0 + qt*16 + lr;
        *(uint2*)(O + ((size_t)b*NT_ + tok)*C_ + h*D_ + dc*16 + lg*4) = o.v;
      }
    }
  }
}

// ---------------- host ----------------
extern "C" void kernel_launch(void* const* d_in, const int* in_sizes, int n_in,
                              void* d_out, int out_size, void* d_ws, size_t ws_size,
                              hipStream_t stream)
{
  (void)in_sizes; (void)n_in; (void)out_size; (void)ws_size;
  const float* x        = (const float*)d_in[0];
  const float* c        = (const float*)d_in[1];
  const float* gc       = (const float*)d_in[2];
  const float* ada_x_w  = (const float*)d_in[3];
  const float* ada_x_b  = (const float*)d_in[4];
  const float* ada_c_w  = (const float*)d_in[5];
  const float* ada_c_b  = (const float*)d_in[6];
  const float* g1x_g    = (const float*)d_in[7];
  const float* g1x_b    = (const float*)d_in[8];
  const float* g2x_g    = (const float*)d_in[9];
  const float* g2x_b    = (const float*)d_in[10];
  const float* g1c_g    = (const float*)d_in[11];
  const float* g1c_b    = (const float*)d_in[12];
  const float* g2c_g    = (const float*)d_in[13];
  const float* g2c_b    = (const float*)d_in[14];
  const float* qkv_x_w  = (const float*)d_in[15];
  const float* qkv_x_b  = (const float*)d_in[16];
  const float* proj_x_w = (const float*)d_in[17];
  const float* proj_x_b = (const float*)d_in[18];
  const float* qkv_c_w  = (const float*)d_in[19];
  const float* qkv_c_b  = (const float*)d_in[20];
  const float* proj_c_w = (const float*)d_in[21];
  const float* proj_c_b = (const float*)d_in[22];
  const float* gq_x     = (const float*)d_in[23];
  const float* gk_x     = (const float*)d_in[24];
  const float* gq_c     = (const float*)d_in[25];
  const float* gk_c     = (const float*)d_in[26];
  const float* m_x_w1   = (const float*)d_in[27];
  const float* m_x_b1   = (const float*)d_in[28];
  const float* m_x_w2   = (const float*)d_in[29];
  const float* m_x_b2   = (const float*)d_in[30];
  const float* m_c_w1   = (const float*)d_in[31];
  const float* m_c_b1   = (const float*)d_in[32];
  const float* m_c_w2   = (const float*)d_in[33];
  const float* m_c_b2   = (const float*)d_in[34];
  float* out = (float*)d_out;

  char* ws = (char*)d_ws;
  size_t off = 0;
  auto alloc = [&](size_t bytes)->void*{ void* p = ws + off; off += (bytes + 255) & ~(size_t)255; return p; };
  u16* WTqx  = (u16*)alloc((size_t)3456*1152*2);
  u16* WTqc  = (u16*)alloc((size_t)3456*1152*2);
  u16* WTpx  = (u16*)alloc((size_t)1152*1152*2);
  u16* WTpc  = (u16*)alloc((size_t)1152*1152*2);
  u16* WTm1x = (u16*)alloc((size_t)4608*1152*2);
  u16* WTm2x = (u16*)alloc((size_t)1152*4608*2);
  u16* WTm1c = (u16*)alloc((size_t)4608*1152*2);
  u16* WTm2c = (u16*)alloc((size_t)1152*4608*2);
  float* mod_x = (float*)alloc((size_t)4*6912*4);
  float* mod_c = (float*)alloc((size_t)4*6912*4);
  u16* xin  = (u16*)alloc((size_t)4608*1152*2);
  u16* pool = (u16*)alloc((size_t)4608*4608*2);     // qkv out, later MLP hidden
  u16* qpad = (u16*)alloc((size_t)64*1152*96*2 + 4096);
  u16* kpad = (u16*)alloc((size_t)64*1152*96*2 + 4096);
  u16* vTb  = (u16*)alloc((size_t)64*80*1152*2 + 4096);
  u16* Obuf = (u16*)alloc((size_t)4*1152*1152*2);
  float* x1c1 = (float*)alloc((size_t)4608*1152*4);
  // split-K partial buffers reuse dead spans:
  //  - fc2:  p0 = qpad span, p1 = qpad span + 21.2MB (fits qpad..Obuf = 50+ MB, all dead at L9a)
  //  - proj: p0 = qpad span (21.2MB <= qpad+kpad = 28.9MB, dead after attn), p1 = x1c1 (dead before proj;
  //          reduce2 reads p1[i] before writing out[i] at the same address -> safe aliasing)
  float* fc2p0 = (float*)qpad;
  float* fc2p1 = fc2p0 + (size_t)MT_*C_;
  float* projp0 = (float*)qpad;

  // L0: weight transposes (fp32 -> bf16 [N][K])
  {
    TrArgs ta;
    const float* srcs[8] = {qkv_x_w, qkv_c_w, proj_x_w, proj_c_w, m_x_w1, m_x_w2, m_c_w1, m_c_w2};
    u16* dsts[8]         = {WTqx, WTqc, WTpx, WTpc, WTm1x, WTm2x, WTm1c, WTm2c};
    int Ks[8] = {1152,1152,1152,1152,1152,4608,1152,4608};
    int Ns[8] = {3456,3456,1152,1152,4608,1152,4608,1152};
    int st = 0;
    for (int i = 0; i < 8; ++i){
      ta.src[i] = srcs[i]; ta.dst[i] = dsts[i]; ta.K[i] = Ks[i]; ta.N[i] = Ns[i];
      ta.start[i] = st; st += (Ks[i]/32)*(Ns[i]/32);
    }
    ta.start[8] = st;
    transpose_kernel<<<dim3(st), dim3(256), 0, stream>>>(ta);
  }
  // L1: adaLN modulation vectors
  ada_kernel<<<dim3(216), dim3(256), 0, stream>>>(gc, ada_x_w, ada_x_b, ada_c_w, ada_c_b, mod_x, mod_c);
  // L2: LN1 + modulate
  ln_mod_kernel<<<dim3(4608), dim3(256), 0, stream>>>(
      x, c, g1x_g, g1x_b, g1c_g, g1c_b,
      mod_x + 0, mod_x + 1152, mod_c + 0, mod_c + 1152, xin);
  // L3: qkv GEMM (merged x|c)
  {
    GemmArgs ga{};
    ga.A = xin; ga.lda = 1152; ga.rowmap = 0;
    ga.BTx = WTqx; ga.BTc = WTqc; ga.biasx = qkv_x_b; ga.biasc = qkv_c_b;
    ga.outx = pool; ga.outc = pool + (size_t)4096*3456;
    ga.N = 3456; ga.K = 1152; ga.kLen = 1152;
    gemm_kernel<0><<<dim3(27,36), dim3(256), 0, stream>>>(ga);
  }
  // L4: head split + RMS + pad + V^T (+ones row, q pre-scaled incl. log2e)
  rmshead_kernel<<<dim3(18,16,4), dim3(256), 0, stream>>>(pool, gq_x, gk_x, gq_c, gk_c, qpad, kpad, vTb);
  // L5: attention (XCD-chunked 1D grid, R10 structure)
  attn_kernel<<<dim3(576), dim3(256), 0, stream>>>(qpad, kpad, vTb, Obuf);
  // L6a: proj split-K=2 -> raw fp32 partials (qpad span dead after attn; z=1 -> x1c1)
  {
    GemmArgs ga{};
    ga.A = Obuf; ga.lda = 1152; ga.rowmap = 1;
    ga.BTx = WTpx; ga.BTc = WTpc;
    ga.outx = projp0; ga.outc = x1c1;
    ga.N = 1152; ga.K = 1152; ga.kLen = 576;
    gemm_kernel<3><<<dim3(9,36,2), dim3(256), 0, stream>>>(ga);
  }
  // L6b: reduce partials + bias + gate + residual -> x1c1 (p1 aliases out; elementwise safe)
  reduce2_kernel<<<dim3(2048), dim3(256), 0, stream>>>(
      projp0, x1c1, x, c,
      mod_x + 2*1152, mod_c + 2*1152, proj_x_b, proj_c_b,
      x1c1, x1c1 + (size_t)4096*1152);
  // L7: LN2 + modulate (reads fp32 x1c1)
  ln_mod_kernel<<<dim3(4608), dim3(256), 0, stream>>>(
      x1c1, x1c1 + (size_t)4096*1152, g2x_g, g2x_b, g2c_g, g2c_b,
      mod_x + 3*1152, mod_x + 4*1152, mod_c + 3*1152, mod_c + 4*1152, xin);
  // L8: MLP fc1 + GELU
  {
    GemmArgs ga{};
    ga.A = xin; ga.lda = 1152; ga.rowmap = 0;
    ga.BTx = WTm1x; ga.BTc = WTm1c; ga.biasx = m_x_b1; ga.biasc = m_c_b1;
    ga.outx = pool; ga.outc = pool + (size_t)4096*4608;
    ga.N = 4608; ga.K = 1152; ga.kLen = 1152;
    gemm_kernel<1><<<dim3(36,36), dim3(256), 0, stream>>>(ga);
  }
  // L9a: MLP fc2 split-K=2 -> raw fp32 partials (no atomics)
  {
    GemmArgs ga{};
    ga.A = pool; ga.lda = 4608; ga.rowmap = 0;
    ga.BTx = WTm2x; ga.BTc = WTm2c;
    ga.outx = fc2p0; ga.outc = fc2p1;
    ga.N = 1152; ga.K = 4608; ga.kLen = 2304;
    gemm_kernel<3><<<dim3(9,36,2), dim3(256), 0, stream>>>(ga);
  }
  // L9b: reduce partials + bias + gate + residual -> d_out
  reduce2_kernel<<<dim3(2048), dim3(256), 0, stream>>>(
      fc2p0, fc2p1, x1c1, x1c1 + (size_t)4096*1152,
      mod_x + 5*1152, mod_c + 5*1152, m_x_b2, m_c_b2,
      out, out + (size_t)4096*1152);
}

// Round 13
// 445.851 us; speedup vs baseline: 1.0879x; 1.0046x over previous
//
#include <hip/hip_runtime.h>

typedef unsigned short u16;
typedef unsigned int u32;
typedef __attribute__((ext_vector_type(8))) short bf16x8;
typedef __attribute__((ext_vector_type(4))) float f32x4;

#define MX_ 4096      // B*N1 rows of x-stream
#define NT_ 1152      // N1+N2 tokens
#define C_  1152
#define DP_ 96        // padded head dim for QK contraction
#define D_  72
#define H_  16
#define MT_ 4608      // total rows (x 4096 + c 512)

static __device__ __forceinline__ float b2f(u16 u){ union{u32 i; float f;} x; x.i=((u32)u)<<16; return x.f; }
static __device__ __forceinline__ u16 f2b(float f){ u32 i=__float_as_uint(f); return (u16)((i + 0x7FFFu + ((i>>16)&1u))>>16); }

static __device__ __forceinline__ void gl_lds16(const u16* g, u16* l){
  __builtin_amdgcn_global_load_lds((const __attribute__((address_space(1))) void*)g,
                                   (__attribute__((address_space(3))) void*)l, 16, 0, 0);
}

#define MFMA16(a,b,c) __builtin_amdgcn_mfma_f32_16x16x32_bf16(a,b,c,0,0,0)

// ---------------- transpose (K,N) fp32 -> (N,K) bf16; vectorized uint2 writes ----------------
struct TrArgs {
  const float* src[8]; u16* dst[8]; int K[8]; int N[8]; int start[9];
};

__global__ __launch_bounds__(256) void transpose_kernel(TrArgs a){
  int bx = blockIdx.x;
  int mi = 0;
  #pragma unroll
  for (int i = 0; i < 8; ++i) if (bx >= a.start[i+1]) mi = i+1;
  int t = bx - a.start[mi];
  int K = a.K[mi], N = a.N[mi];
  int ntk = K >> 5;
  int tk = t % ntk, tn = t / ntk;
  int k0 = tk*32, n0 = tn*32;
  __shared__ u16 lds[32][33];
  int c = threadIdx.x & 31, r = threadIdx.x >> 5;
  const float* src = a.src[mi];
  u16* dst = a.dst[mi];
  #pragma unroll
  for (int ii = 0; ii < 4; ++ii){
    int row = r + ii*8;
    lds[row][c] = f2b(src[(size_t)(k0+row)*N + n0 + c]);
  }
  __syncthreads();
  // write phase: 32 n-rows x 8 k-groups; each lane stores 4 u16 = uint2 (256B/wave coalesced)
  {
    int n = threadIdx.x >> 3, kg = threadIdx.x & 7;
    union { uint2 v; u16 e[4]; } o;
    #pragma unroll
    for (int j = 0; j < 4; ++j) o.e[j] = lds[kg*4 + j][n];
    *(uint2*)(dst + (size_t)(n0+n)*K + k0 + kg*4) = o.v;
  }
}

// ---------------- adaLN: s = silu(global_c); mod = s @ ada_w + ada_b (fp32 out) ----------------
__global__ __launch_bounds__(256) void ada_kernel(const float* gc, const float* wx, const float* bx,
                                                  const float* wc, const float* bc,
                                                  float* mod_x, float* mod_c){
  __shared__ float s[4][C_];
  __shared__ float part[4][4][64];
  int tid = threadIdx.x;
  for (int i = tid; i < 4*C_; i += 256){
    float v = gc[i];
    s[i / C_][i % C_] = v / (1.f + __expf(-v));
  }
  __syncthreads();
  int jq = tid & 63;
  int kq = tid >> 6;
  int jg = blockIdx.x*64 + jq;
  int which = jg / 6912;
  int j = jg % 6912;
  const float* W = which ? wc : wx;
  float a0=0.f, a1=0.f, a2=0.f, a3=0.f;
  for (int k = kq*288; k < kq*288 + 288; ++k){
    float w = W[(size_t)k*6912 + j];
    a0 += s[0][k]*w; a1 += s[1][k]*w; a2 += s[2][k]*w; a3 += s[3][k]*w;
  }
  part[kq][0][jq]=a0; part[kq][1][jq]=a1; part[kq][2][jq]=a2; part[kq][3][jq]=a3;
  __syncthreads();
  if (kq == 0){
    float bb = (which ? bc : bx)[j];
    float* out = which ? mod_c : mod_x;
    #pragma unroll
    for (int b = 0; b < 4; ++b){
      out[(size_t)b*6912 + j] = part[0][b][jq] + part[1][b][jq] + part[2][b][jq] + part[3][b][jq] + bb;
    }
  }
}

// ---------------- fused LayerNorm + modulate (fp32 in, bf16 out) ----------------
__global__ __launch_bounds__(256) void ln_mod_kernel(
  const float* srcx, const float* srcc, const float* g, const float* bt,
  const float* gcn, const float* btc,
  const float* shx, const float* scx, const float* shc, const float* scc,
  u16* out)
{
  int m = blockIdx.x;
  bool isC = (m >= MX_);
  const float* src = isC ? srcc + (size_t)(m - MX_)*C_ : srcx + (size_t)m*C_;
  int bidx = isC ? ((m - MX_) >> 7) : (m >> 10);
  const float* gg = isC ? gcn : g;
  const float* bb = isC ? btc : bt;
  const float* sh = (isC ? shc : shx) + (size_t)bidx*6912;
  const float* sc = (isC ? scc : scx) + (size_t)bidx*6912;
  int tid = threadIdx.x;
  float lv[8];
  float sum = 0.f, sq = 0.f;
  if (tid < 144){
    float4 v0 = *(const float4*)(src + tid*8);
    float4 v1 = *(const float4*)(src + tid*8 + 4);
    lv[0]=v0.x; lv[1]=v0.y; lv[2]=v0.z; lv[3]=v0.w;
    lv[4]=v1.x; lv[5]=v1.y; lv[6]=v1.z; lv[7]=v1.w;
    #pragma unroll
    for (int j = 0; j < 8; ++j){ sum += lv[j]; sq += lv[j]*lv[j]; }
  }
  #pragma unroll
  for (int off = 1; off < 64; off <<= 1){ sum += __shfl_xor(sum, off); sq += __shfl_xor(sq, off); }
  __shared__ float rs[4], rq[4];
  int wave = tid >> 6, lane = tid & 63;
  if (lane == 0){ rs[wave] = sum; rq[wave] = sq; }
  __syncthreads();
  float S = rs[0]+rs[1]+rs[2]+rs[3];
  float Q = rq[0]+rq[1]+rq[2]+rq[3];
  float mean = S * (1.f/1152.f);
  float var  = Q * (1.f/1152.f) - mean*mean;
  float rstd = rsqrtf(var + 1e-6f);
  if (tid < 144){
    union { uint4 v; u16 s[8]; } o;
    #pragma unroll
    for (int j = 0; j < 8; ++j){
      int n = tid*8 + j;
      float val = (lv[j] - mean)*rstd*gg[n] + bb[n];
      val = val*(1.f + sc[n]) + sh[n];
      o.s[j] = f2b(val);
    }
    *(uint4*)(out + (size_t)m*C_ + tid*8) = o.v;
  }
}

// ---------------- split-K reduce: out = resid + gate*(p0+p1+bias) ----------------
// p0, p1 are separate [4608][1152] raw partial buffers (p1 may alias out: read-before-write per elem)
__global__ __launch_bounds__(256) void reduce2_kernel(
  const float* p0, const float* p1,
  const float* residx, const float* residc,
  const float* modx, const float* modc,
  const float* biasx, const float* biasc,
  float* outx, float* outc)
{
  for (int i4 = blockIdx.x*256 + threadIdx.x; i4 < MT_*288; i4 += gridDim.x*256){
    int m = i4 / 288, n4 = (i4 % 288)*4;
    bool isC = (m >= MX_);
    int bidx = isC ? ((m - MX_) >> 7) : (m >> 10);
    const float* gate  = (isC ? modc : modx) + (size_t)bidx*6912;
    const float* bias  = isC ? biasc : biasx;
    const float* resid = isC ? residc + (size_t)(m - MX_)*C_ : residx + (size_t)m*C_;
    float* o = isC ? outc + (size_t)(m - MX_)*C_ : outx + (size_t)m*C_;
    float4 a = *(const float4*)(p0 + (size_t)m*C_ + n4);
    float4 b = *(const float4*)(p1 + (size_t)m*C_ + n4);
    float4 r = *(const float4*)(resid + n4);
    float4 ov;
    ov.x = r.x + gate[n4+0]*(a.x + b.x + bias[n4+0]);
    ov.y = r.y + gate[n4+1]*(a.y + b.y + bias[n4+1]);
    ov.z = r.z + gate[n4+2]*(a.z + b.z + bias[n4+2]);
    ov.w = r.w + gate[n4+3]*(a.w + b.w + bias[n4+3]);
    *(float4*)(o + n4) = ov;
  }
}

// ---------------- GEMM: C = A @ B(^T stored), single-buffer 32KB, XCD-swizzled ----------------
// EPI 0: bias -> bf16; EPI 1: gelu(bias+acc) -> bf16; EPI 2: resid + gate*(acc+bias) -> f32
// EPI 3: raw acc -> f32 partial (z=0 -> outx, z=1 -> outc; bias/resid/gate in reduce2)
struct GemmArgs {
  const u16* A; int lda; int rowmap;       // rowmap 1 = O-buffer token map
  const u16* BTx; const u16* BTc;          // [N][K] bf16 row-major (pre-transposed)
  const float* biasx; const float* biasc;
  void* outx; void* outc;
  const float* residx; const float* residc;
  const float* gatex; const float* gatec;  // + b*6912 applied inside
  int N, K, kLen;
};

static __device__ __forceinline__ int amap(int m, int rowmap){
  if (rowmap){
    if (m < MX_) return (m >> 10)*NT_ + (m & 1023);
    int mm = m - MX_;
    return (mm >> 7)*NT_ + 1024 + (mm & 127);
  }
  return m;
}

template<int EPI>
__global__ __launch_bounds__(256, 2) void gemm_kernel(GemmArgs g){
  __shared__ u16 As[128*64];
  __shared__ u16 Bs[128*64];
  // m204 bijective XCD-chunked swizzle: contiguous by-bands per XCD (A-band/XCD unique, B streams)
  int gx = gridDim.x, gy = gridDim.y;
  int nwg = gx*gy;
  int orig = blockIdx.y*gx + blockIdx.x;
  int q = nwg >> 3, r8 = nwg & 7;
  int xcd = orig & 7, wi = orig >> 3;
  int swz = (xcd < r8 ? xcd*(q+1) : r8*(q+1) + (xcd - r8)*q) + wi;
  int n0 = (swz % gx)*128, m0 = (swz / gx)*128;
  int kStart = blockIdx.z * g.kLen;
  bool isC = (m0 >= MX_);
  const u16* BT = isC ? g.BTc : g.BTx;
  int tid = threadIdx.x, wave = tid >> 6, lane = tid & 63;
  int lg = lane >> 4, lr = lane & 15;
  int wm = wave >> 1, wn = wave & 1;
  f32x4 acc[4][4] = {};

  // hoisted per-lane staging source addresses (k offset added per step)
  const u16* Aaddr[4]; const u16* Baddr[4];
  #pragma unroll
  for (int i = 0; i < 4; ++i){
    int cb = (wave*4 + i)*64;
    int qq = cb + lane;
    int row = qq >> 3;
    int c16 = (qq & 7) ^ (row & 7);           // XOR-swizzle: both-sides (source pre-swizzled)
    Aaddr[i] = g.A + (size_t)amap(m0 + row, g.rowmap)*g.lda + kStart + c16*8;
    Baddr[i] = BT + (size_t)(n0 + row)*g.K + kStart + c16*8;
  }
  for (int k0 = 0; k0 < g.kLen; k0 += 64){
    #pragma unroll
    for (int i = 0; i < 4; ++i){
      int cb = (wave*4 + i)*64;
      gl_lds16(Aaddr[i] + k0, As + cb*8);
      gl_lds16(Baddr[i] + k0, Bs + cb*8);
    }
    __syncthreads();
    #pragma unroll
    for (int kkI = 0; kkI < 2; ++kkI){
      bf16x8 af[4], bfr[4];
      #pragma unroll
      for (int mi = 0; mi < 4; ++mi){
        int row = wm*64 + mi*16 + lr;
        int c16 = (kkI*4 + lg) ^ (row & 7);
        af[mi] = *(const bf16x8*)&As[row*64 + c16*8];
      }
      #pragma unroll
      for (int ni = 0; ni < 4; ++ni){
        int row = wn*64 + ni*16 + lr;
        int c16 = (kkI*4 + lg) ^ (row & 7);
        bfr[ni] = *(const bf16x8*)&Bs[row*64 + c16*8];
      }
      #pragma unroll
      for (int mi = 0; mi < 4; ++mi)
        #pragma unroll
        for (int ni = 0; ni < 4; ++ni)
          acc[mi][ni] = MFMA16(af[mi], bfr[ni], acc[mi][ni]);
    }
    __syncthreads();
  }

  // epilogue
  const float* bias  = isC ? g.biasc : g.biasx;
  const float* resid = isC ? g.residc : g.residx;
  void* out = isC ? g.outc : g.outx;
  const float* gate = nullptr;
  if (EPI == 2){
    int bidx = isC ? ((m0 - MX_) >> 7) : (m0 >> 10);
    gate = (isC ? g.gatec : g.gatex) + (size_t)bidx*6912;
  }
  int mbase = isC ? (m0 - MX_) : m0;
  float* pbase = nullptr;
  if (EPI == 3) pbase = blockIdx.z ? (float*)g.outc : (float*)g.outx;
  #pragma unroll
  for (int mi = 0; mi < 4; ++mi){
    #pragma unroll
    for (int r = 0; r < 4; ++r){
      #pragma unroll
      for (int ni = 0; ni < 4; ++ni){
        int n = n0 + wn*64 + ni*16 + lr;
        if (EPI == 3){
          size_t prow = (size_t)(m0 + wm*64 + mi*16 + lg*4 + r);
          pbase[prow*(size_t)g.N + n] = acc[mi][ni][r];
        } else {
          size_t orow = (size_t)(mbase + wm*64 + mi*16 + lg*4 + r);
          float v = acc[mi][ni][r] + bias[n];
          if (EPI == 1){
            float u = 0.7978845608028654f*(v + 0.044715f*v*v*v);
            v = 0.5f*v*(1.f + tanhf(u));
          }
          if (EPI == 2){
            v = resid[orow*(size_t)g.N + n] + gate[n]*v;
            ((float*)out)[orow*(size_t)g.N + n] = v;
          } else {
            ((u16*)out)[orow*(size_t)g.N + n] = f2b(v);
          }
        }
      }
    }
  }
}

// ---------------- head split + RMS-norm(q,k) + pad + V transpose ----------------
// q scaled by ATTN_SCALE*log2(e) (softmax runs in exp2 domain); vT row 72 = 1.0 (ones-row
// accumulates l alongside O with identical rescaling), rows 73-79 = 0
__global__ __launch_bounds__(256) void rmshead_kernel(
  const u16* qkv, const float* gqx, const float* gkx, const float* gqc, const float* gkc,
  u16* qpad, u16* kpad, u16* vT)
{
  int tt = blockIdx.x, h = blockIdx.y, b = blockIdx.z;
  int t0 = tt*64;
  bool isC = (t0 >= 1024);
  size_t rowbase = isC ? (size_t)(MX_ + b*128 + (t0 - 1024)) : (size_t)(b*1024 + t0);
  __shared__ u16 sq[2][64][72];
  __shared__ u16 sv[64][72];
  __shared__ float nf[2][64];
  int tid = threadIdx.x;
  for (int s = tid; s < 1728; s += 256){
    int which = s / 576, rem = s % 576;
    int t = rem / 9, ch = rem % 9;
    uint4 v = *(const uint4*)(qkv + (rowbase + t)*3456 + which*C_ + h*D_ + ch*8);
    u16* dst = (which < 2) ? &sq[which][t][ch*8] : &sv[t][ch*8];
    *(uint4*)dst = v;
  }
  __syncthreads();
  {
    int row = tid >> 1, half = tid & 1;
    int which = row >> 6, t = row & 63;
    float ss = 0.f;
    for (int d = half*36; d < half*36 + 36; ++d){
      float v = b2f(sq[which][t][d]); ss += v*v;
    }
    ss += __shfl_xor(ss, 1);
    if (half == 0){
      const float* gp = (which == 0) ? (isC ? gqc : gqx) : (isC ? gkc : gkx);
      float f = 33.9411254970f * gp[0] / fmaxf(sqrtf(ss), 1e-12f);
      if (which == 0) f *= 0.17002324581205f;   // ATTN_SCALE * log2(e) folded into q
      nf[which][t] = f;
    }
  }
  __syncthreads();
  size_t obase = ((size_t)(b*H_ + h)*NT_ + t0) * DP_;
  for (int s = tid; s < 1536; s += 256){
    int which = s / 768, rem = s % 768;
    int t = rem / 12, ch = rem % 12;
    float f = nf[which][t];
    union { uint4 v; u16 e[8]; } o;
    #pragma unroll
    for (int j = 0; j < 8; ++j){
      int d = ch*8 + j;
      o.e[j] = (d < D_) ? f2b(b2f(sq[which][t][d]) * f) : (u16)0;
    }
    *(uint4*)((which == 0 ? qpad : kpad) + obase + (size_t)t*DP_ + ch*8) = o.v;
  }
  size_t vbase = (size_t)(b*H_ + h)*80*NT_;
  for (int s = tid; s < 576; s += 256){
    int d = s / 8, ch = s % 8;
    union { uint4 v; u16 e[8]; } o;
    #pragma unroll
    for (int j = 0; j < 8; ++j) o.e[j] = sv[ch*8 + j][d];
    *(uint4*)(vT + vbase + (size_t)d*NT_ + t0 + ch*8) = o.v;
  }
  // pad rows: d=72 -> 1.0 (ones row => PV accumulates row-sum l), d=73..79 -> 0
  for (int s = tid; s < 512; s += 256){
    int d = 72 + (s >> 6), t = s & 63;
    vT[vbase + (size_t)d*NT_ + t0 + t] = (d == 72) ? (u16)0x3F80 : (u16)0;
  }
}

// ---------------- attention: 32 q-rows/wave, XCD-chunked, barrier-free ----------------
// R10/R12 structure. amdgpu_waves_per_eu(1,2): attn is GRID-limited at 2.25 waves/SIMD,
// so per-wave VGPR up to 256 is free -- raise the allocator budget (min-occupancy 1 wave/EU)
// so the full ~196-reg dbuf working set stays live and the 11 per-tile loads pipeline
// instead of serializing (the 114us plateau). NOTE: __launch_bounds__(256,N) was the WRONG
// tool (R9: it SHRANK the budget to 84 + scratch spills).
__global__ __launch_bounds__(256) __attribute__((amdgpu_waves_per_eu(1, 2))) void attn_kernel(
  const u16* qpad, const u16* kpad, const u16* vT, u16* O)
{
  __shared__ u16 Ps[4][32][40];     // per-wave P, stride 40 u16 (5x16B, odd => conflict-free b128)
  int orig = blockIdx.x;
  int w = (orig & 7)*72 + (orig >> 3);
  int qtb = w % 9, hb = w / 9;
  int h = hb & 15, b = hb >> 4;
  int bh = b*H_ + h;
  int tid = threadIdx.x, wave = tid >> 6, lane = tid & 63;
  int lg = lane >> 4, lr = lane & 15;
  int q0 = qtb*128 + wave*32;

  const u16* qb = qpad + (size_t)bh*NT_*DP_;
  const u16* kb = kpad + (size_t)bh*NT_*DP_;
  const u16* vb = vT + (size_t)bh*80*NT_;

  bf16x8 qf[2][3];
  #pragma unroll
  for (int qt = 0; qt < 2; ++qt)
    #pragma unroll
    for (int kk = 0; kk < 3; ++kk)
      qf[qt][kk] = *(const bf16x8*)(qb + (size_t)(q0 + qt*16 + lr)*DP_ + kk*32 + lg*8);

  f32x4 acc[5][2] = {};
  float m0 = -1e30f, m1 = -1e30f;

  bf16x8 kfA[2][3], kfB[2][3], vf[5];
  auto LOADK = [&](bf16x8 (&kf)[2][3], int kvt){
    #pragma unroll
    for (int kt = 0; kt < 2; ++kt)
      #pragma unroll
      for (int kk = 0; kk < 3; ++kk)
        kf[kt][kk] = *(const bf16x8*)(kb + (size_t)(kvt*32 + kt*16 + lr)*DP_ + kk*32 + lg*8);
  };
  u16* prow0 = &Ps[wave][lr][0];
  u16* prow1 = &Ps[wave][16 + lr][0];

  auto TILE = [&](bf16x8 (&kf)[2][3], bf16x8 (&kfn)[2][3], int t){
    #pragma unroll
    for (int dc = 0; dc < 5; ++dc)
      vf[dc] = *(const bf16x8*)(vb + (size_t)(dc*16 + lr)*NT_ + t*32 + lg*8);
    if (t + 1 < 36) LOADK(kfn, t + 1);

    f32x4 st[2][2] = {};
    __builtin_amdgcn_s_setprio(1);
    #pragma unroll
    for (int kk = 0; kk < 3; ++kk){
      st[0][0] = MFMA16(kf[0][kk], qf[0][kk], st[0][0]);
      st[0][1] = MFMA16(kf[0][kk], qf[1][kk], st[0][1]);
      st[1][0] = MFMA16(kf[1][kk], qf[0][kk], st[1][0]);
      st[1][1] = MFMA16(kf[1][kk], qf[1][kk], st[1][1]);
    }
    __builtin_amdgcn_s_setprio(0);

    // defer-max online softmax in exp2 domain (threshold 8*log2e)
    float pm0 = fmaxf(fmaxf(fmaxf(st[0][0][0], st[0][0][1]), fmaxf(st[0][0][2], st[0][0][3])),
                      fmaxf(fmaxf(st[1][0][0], st[1][0][1]), fmaxf(st[1][0][2], st[1][0][3])));
    float pm1 = fmaxf(fmaxf(fmaxf(st[0][1][0], st[0][1][1]), fmaxf(st[0][1][2], st[0][1][3])),
                      fmaxf(fmaxf(st[1][1][0], st[1][1][1]), fmaxf(st[1][1][2], st[1][1][3])));
    float tt = fmaxf(pm0 - m0, pm1 - m1);
    if (!__all(tt <= 11.5415603f)){
      float r0 = fmaxf(pm0, __shfl_xor(pm0, 16)); r0 = fmaxf(r0, __shfl_xor(r0, 32));
      float r1 = fmaxf(pm1, __shfl_xor(pm1, 16)); r1 = fmaxf(r1, __shfl_xor(r1, 32));
      float n0 = fmaxf(m0, r0), n1 = fmaxf(m1, r1);
      float f0 = exp2f(m0 - n0), f1 = exp2f(m1 - n1);
      m0 = n0; m1 = n1;
      #pragma unroll
      for (int dc = 0; dc < 5; ++dc)
        #pragma unroll
        for (int j = 0; j < 4; ++j){ acc[dc][0][j] *= f0; acc[dc][1][j] *= f1; }
    }
    // P = exp2(s' - m') -> bf16 via v_cvt_pk (RNE) -> LDS (wave-private rows)
    #pragma unroll
    for (int kt = 0; kt < 2; ++kt){
      #pragma unroll
      for (int qt = 0; qt < 2; ++qt){
        float mm = qt ? m1 : m0;
        float e0 = exp2f(st[kt][qt][0] - mm);
        float e1 = exp2f(st[kt][qt][1] - mm);
        float e2 = exp2f(st[kt][qt][2] - mm);
        float e3 = exp2f(st[kt][qt][3] - mm);
        u32 lo, hi;
        asm("v_cvt_pk_bf16_f32 %0, %1, %2" : "=v"(lo) : "v"(e0), "v"(e1));
        asm("v_cvt_pk_bf16_f32 %0, %1, %2" : "=v"(hi) : "v"(e2), "v"(e3));
        uint2 pkd; pkd.x = lo; pkd.y = hi;
        *(uint2*)((qt ? prow1 : prow0) + kt*16 + lg*4) = pkd;
      }
    }
    // ORDER FENCE (rule #18): pin ds_writes above / ds_reads below, drain LDS writes
    asm volatile("s_waitcnt lgkmcnt(0)" ::: "memory");
    __builtin_amdgcn_sched_barrier(0);
    bf16x8 bp0 = *(const bf16x8*)(prow0 + lg*8);
    bf16x8 bp1 = *(const bf16x8*)(prow1 + lg*8);
    __builtin_amdgcn_s_setprio(1);
    #pragma unroll
    for (int dc = 0; dc < 5; ++dc){
      acc[dc][0] = MFMA16(vf[dc], bp0, acc[dc][0]);
      acc[dc][1] = MFMA16(vf[dc], bp1, acc[dc][1]);
    }
    __builtin_amdgcn_s_setprio(0);
  };

  LOADK(kfA, 0);
  for (int t2 = 0; t2 < 18; ++t2){
    TILE(kfA, kfB, 2*t2);
    TILE(kfB, kfA, 2*t2 + 1);
  }

  float l0 = __shfl(acc[4][0][0], 32 + lr);
  float l1 = __shfl(acc[4][1][0], 32 + lr);
  float rl0 = 1.f / l0, rl1 = 1.f / l1;
  #pragma unroll
  for (int dc = 0; dc < 5; ++dc){
    #pragma unroll
    for (int qt = 0; qt < 2; ++qt){
      if (dc < 4 || lg < 2){
        float rl = qt ? rl1 : rl0;
        union { uint2 v; u16 e[4]; } o;
        #pragma unroll
        for (int j = 0; j < 4; ++j) o.e[j] = f2b(acc[dc][qt][j] * rl);
        int tok = q0 + qt*16 + lr;
        *(uint2*)(O + ((size_t)b*NT_ + tok)*C_ + h*D_ + dc*16 + lg*4) = o.v;
      }
    }
  }
}

// ---------------- host ----------------
extern "C" void kernel_launch(void* const* d_in, const int* in_sizes, int n_in,
                              void* d_out, int out_size, void* d_ws, size_t ws_size,
                              hipStream_t stream)
{
  (void)in_sizes; (void)n_in; (void)out_size; (void)ws_size;
  const float* x        = (const float*)d_in[0];
  const float* c        = (const float*)d_in[1];
  const float* gc       = (const float*)d_in[2];
  const float* ada_x_w  = (const float*)d_in[3];
  const float* ada_x_b  = (const float*)d_in[4];
  const float* ada_c_w  = (const float*)d_in[5];
  const float* ada_c_b  = (const float*)d_in[6];
  const float* g1x_g    = (const float*)d_in[7];
  const float* g1x_b    = (const float*)d_in[8];
  const float* g2x_g    = (const float*)d_in[9];
  const float* g2x_b    = (const float*)d_in[10];
  const float* g1c_g    = (const float*)d_in[11];
  const float* g1c_b    = (const float*)d_in[12];
  const float* g2c_g    = (const float*)d_in[13];
  const float* g2c_b    = (const float*)d_in[14];
  const float* qkv_x_w  = (const float*)d_in[15];
  const float* qkv_x_b  = (const float*)d_in[16];
  const float* proj_x_w = (const float*)d_in[17];
  const float* proj_x_b = (const float*)d_in[18];
  const float* qkv_c_w  = (const float*)d_in[19];
  const float* qkv_c_b  = (const float*)d_in[20];
  const float* proj_c_w = (const float*)d_in[21];
  const float* proj_c_b = (const float*)d_in[22];
  const float* gq_x     = (const float*)d_in[23];
  const float* gk_x     = (const float*)d_in[24];
  const float* gq_c     = (const float*)d_in[25];
  const float* gk_c     = (const float*)d_in[26];
  const float* m_x_w1   = (const float*)d_in[27];
  const float* m_x_b1   = (const float*)d_in[28];
  const float* m_x_w2   = (const float*)d_in[29];
  const float* m_x_b2   = (const float*)d_in[30];
  const float* m_c_w1   = (const float*)d_in[31];
  const float* m_c_b1   = (const float*)d_in[32];
  const float* m_c_w2   = (const float*)d_in[33];
  const float* m_c_b2   = (const float*)d_in[34];
  float* out = (float*)d_out;

  char* ws = (char*)d_ws;
  size_t off = 0;
  auto alloc = [&](size_t bytes)->void*{ void* p = ws + off; off += (bytes + 255) & ~(size_t)255; return p; };
  u16* WTqx  = (u16*)alloc((size_t)3456*1152*2);
  u16* WTqc  = (u16*)alloc((size_t)3456*1152*2);
  u16* WTpx  = (u16*)alloc((size_t)1152*1152*2);
  u16* WTpc  = (u16*)alloc((size_t)1152*1152*2);
  u16* WTm1x = (u16*)alloc((size_t)4608*1152*2);
  u16* WTm2x = (u16*)alloc((size_t)1152*4608*2);
  u16* WTm1c = (u16*)alloc((size_t)4608*1152*2);
  u16* WTm2c = (u16*)alloc((size_t)1152*4608*2);
  float* mod_x = (float*)alloc((size_t)4*6912*4);
  float* mod_c = (float*)alloc((size_t)4*6912*4);
  u16* xin  = (u16*)alloc((size_t)4608*1152*2);
  u16* pool = (u16*)alloc((size_t)4608*4608*2);     // qkv out, later MLP hidden
  u16* qpad = (u16*)alloc((size_t)64*1152*96*2 + 4096);
  u16* kpad = (u16*)alloc((size_t)64*1152*96*2 + 4096);
  u16* vTb  = (u16*)alloc((size_t)64*80*1152*2 + 4096);
  u16* Obuf = (u16*)alloc((size_t)4*1152*1152*2);
  float* x1c1 = (float*)alloc((size_t)4608*1152*4);
  // split-K partial buffers reuse dead spans:
  //  - fc2:  p0 = qpad span, p1 = qpad span + 21.2MB (fits qpad..Obuf = 50+ MB, all dead at L9a)
  //  - proj: p0 = qpad span (dead after attn), p1 = x1c1 (dead before proj; reduce2 reads
  //          p1[i] before writing out[i] at the same address -> safe aliasing)
  float* fc2p0 = (float*)qpad;
  float* fc2p1 = fc2p0 + (size_t)MT_*C_;
  float* projp0 = (float*)qpad;

  // L0: weight transposes (fp32 -> bf16 [N][K])
  {
    TrArgs ta;
    const float* srcs[8] = {qkv_x_w, qkv_c_w, proj_x_w, proj_c_w, m_x_w1, m_x_w2, m_c_w1, m_c_w2};
    u16* dsts[8]         = {WTqx, WTqc, WTpx, WTpc, WTm1x, WTm2x, WTm1c, WTm2c};
    int Ks[8] = {1152,1152,1152,1152,1152,4608,1152,4608};
    int Ns[8] = {3456,3456,1152,1152,4608,1152,4608,1152};
    int st = 0;
    for (int i = 0; i < 8; ++i){
      ta.src[i] = srcs[i]; ta.dst[i] = dsts[i]; ta.K[i] = Ks[i]; ta.N[i] = Ns[i];
      ta.start[i] = st; st += (Ks[i]/32)*(Ns[i]/32);
    }
    ta.start[8] = st;
    transpose_kernel<<<dim3(st), dim3(256), 0, stream>>>(ta);
  }
  // L1: adaLN modulation vectors
  ada_kernel<<<dim3(216), dim3(256), 0, stream>>>(gc, ada_x_w, ada_x_b, ada_c_w, ada_c_b, mod_x, mod_c);
  // L2: LN1 + modulate
  ln_mod_kernel<<<dim3(4608), dim3(256), 0, stream>>>(
      x, c, g1x_g, g1x_b, g1c_g, g1c_b,
      mod_x + 0, mod_x + 1152, mod_c + 0, mod_c + 1152, xin);
  // L3: qkv GEMM (merged x|c)
  {
    GemmArgs ga{};
    ga.A = xin; ga.lda = 1152; ga.rowmap = 0;
    ga.BTx = WTqx; ga.BTc = WTqc; ga.biasx = qkv_x_b; ga.biasc = qkv_c_b;
    ga.outx = pool; ga.outc = pool + (size_t)4096*3456;
    ga.N = 3456; ga.K = 1152; ga.kLen = 1152;
    gemm_kernel<0><<<dim3(27,36), dim3(256), 0, stream>>>(ga);
  }
  // L4: head split + RMS + pad + V^T (+ones row, q pre-scaled incl. log2e)
  rmshead_kernel<<<dim3(18,16,4), dim3(256), 0, stream>>>(pool, gq_x, gk_x, gq_c, gk_c, qpad, kpad, vTb);
  // L5: attention (XCD-chunked 1D grid, R10 structure + waves_per_eu(1,2))
  attn_kernel<<<dim3(576), dim3(256), 0, stream>>>(qpad, kpad, vTb, Obuf);
  // L6a: proj split-K=2 -> raw fp32 partials (qpad span dead after attn; z=1 -> x1c1)
  {
    GemmArgs ga{};
    ga.A = Obuf; ga.lda = 1152; ga.rowmap = 1;
    ga.BTx = WTpx; ga.BTc = WTpc;
    ga.outx = projp0; ga.outc = x1c1;
    ga.N = 1152; ga.K = 1152; ga.kLen = 576;
    gemm_kernel<3><<<dim3(9,36,2), dim3(256), 0, stream>>>(ga);
  }
  // L6b: reduce partials + bias + gate + residual -> x1c1 (p1 aliases out; elementwise safe)
  reduce2_kernel<<<dim3(2048), dim3(256), 0, stream>>>(
      projp0, x1c1, x, c,
      mod_x + 2*1152, mod_c + 2*1152, proj_x_b, proj_c_b,
      x1c1, x1c1 + (size_t)4096*1152);
  // L7: LN2 + modulate (reads fp32 x1c1)
  ln_mod_kernel<<<dim3(4608), dim3(256), 0, stream>>>(
      x1c1, x1c1 + (size_t)4096*1152, g2x_g, g2x_b, g2c_g, g2c_b,
      mod_x + 3*1152, mod_x + 4*1152, mod_c + 3*1152, mod_c + 4*1152, xin);
  // L8: MLP fc1 + GELU
  {
    GemmArgs ga{};
    ga.A = xin; ga.lda = 1152; ga.rowmap = 0;
    ga.BTx = WTm1x; ga.BTc = WTm1c; ga.biasx = m_x_b1; ga.biasc = m_c_b1;
    ga.outx = pool; ga.outc = pool + (size_t)4096*4608;
    ga.N = 4608; ga.K = 1152; ga.kLen = 1152;
    gemm_kernel<1><<<dim3(36,36), dim3(256), 0, stream>>>(ga);
  }
  // L9a: MLP fc2 split-K=2 -> raw fp32 partials (no atomics)
  {
    GemmArgs ga{};
    ga.A = pool; ga.lda = 4608; ga.rowmap = 0;
    ga.BTx = WTm2x; ga.BTc = WTm2c;
    ga.outx = fc2p0; ga.outc = fc2p1;
    ga.N = 1152; ga.K = 4608; ga.kLen = 2304;
    gemm_kernel<3><<<dim3(9,36,2), dim3(256), 0, stream>>>(ga);
  }
  // L9b: reduce partials + bias + gate + residual -> d_out
  reduce2_kernel<<<dim3(2048), dim3(256), 0, stream>>>(
      fc2p0, fc2p1, x1c1, x1c1 + (size_t)4096*1152,
      mod_x + 5*1152, mod_c + 5*1152, m_x_b2, m_c_b2,
      out, out + (size_t)4096*1152);
}

// Round 14
// 445.303 us; speedup vs baseline: 1.0892x; 1.0012x over previous
//
#include <hip/hip_runtime.h>

typedef unsigned short u16;
typedef unsigned int u32;
typedef __attribute__((ext_vector_type(8))) short bf16x8;
typedef __attribute__((ext_vector_type(4))) float f32x4;

#define MX_ 4096      // B*N1 rows of x-stream
#define NT_ 1152      // N1+N2 tokens
#define C_  1152
#define DP_ 96        // padded head dim for QK contraction
#define D_  72
#define H_  16
#define MT_ 4608      // total rows (x 4096 + c 512)
#define RWS_ 73728    // 64 head-batches * 1152 tokens (attn partial rows)

static __device__ __forceinline__ float b2f(u16 u){ union{u32 i; float f;} x; x.i=((u32)u)<<16; return x.f; }
static __device__ __forceinline__ u16 f2b(float f){ u32 i=__float_as_uint(f); return (u16)((i + 0x7FFFu + ((i>>16)&1u))>>16); }

static __device__ __forceinline__ void gl_lds16(const u16* g, u16* l){
  __builtin_amdgcn_global_load_lds((const __attribute__((address_space(1))) void*)g,
                                   (__attribute__((address_space(3))) void*)l, 16, 0, 0);
}

#define MFMA16(a,b,c) __builtin_amdgcn_mfma_f32_16x16x32_bf16(a,b,c,0,0,0)

// ---------------- transpose (K,N) fp32 -> (N,K) bf16; vectorized uint2 writes ----------------
struct TrArgs {
  const float* src[8]; u16* dst[8]; int K[8]; int N[8]; int start[9];
};

__global__ __launch_bounds__(256) void transpose_kernel(TrArgs a){
  int bx = blockIdx.x;
  int mi = 0;
  #pragma unroll
  for (int i = 0; i < 8; ++i) if (bx >= a.start[i+1]) mi = i+1;
  int t = bx - a.start[mi];
  int K = a.K[mi], N = a.N[mi];
  int ntk = K >> 5;
  int tk = t % ntk, tn = t / ntk;
  int k0 = tk*32, n0 = tn*32;
  __shared__ u16 lds[32][33];
  int c = threadIdx.x & 31, r = threadIdx.x >> 5;
  const float* src = a.src[mi];
  u16* dst = a.dst[mi];
  #pragma unroll
  for (int ii = 0; ii < 4; ++ii){
    int row = r + ii*8;
    lds[row][c] = f2b(src[(size_t)(k0+row)*N + n0 + c]);
  }
  __syncthreads();
  {
    int n = threadIdx.x >> 3, kg = threadIdx.x & 7;
    union { uint2 v; u16 e[4]; } o;
    #pragma unroll
    for (int j = 0; j < 4; ++j) o.e[j] = lds[kg*4 + j][n];
    *(uint2*)(dst + (size_t)(n0+n)*K + k0 + kg*4) = o.v;
  }
}

// ---------------- adaLN: s = silu(global_c); mod = s @ ada_w + ada_b (fp32 out) ----------------
__global__ __launch_bounds__(256) void ada_kernel(const float* gc, const float* wx, const float* bx,
                                                  const float* wc, const float* bc,
                                                  float* mod_x, float* mod_c){
  __shared__ float s[4][C_];
  __shared__ float part[4][4][64];
  int tid = threadIdx.x;
  for (int i = tid; i < 4*C_; i += 256){
    float v = gc[i];
    s[i / C_][i % C_] = v / (1.f + __expf(-v));
  }
  __syncthreads();
  int jq = tid & 63;
  int kq = tid >> 6;
  int jg = blockIdx.x*64 + jq;
  int which = jg / 6912;
  int j = jg % 6912;
  const float* W = which ? wc : wx;
  float a0=0.f, a1=0.f, a2=0.f, a3=0.f;
  for (int k = kq*288; k < kq*288 + 288; ++k){
    float w = W[(size_t)k*6912 + j];
    a0 += s[0][k]*w; a1 += s[1][k]*w; a2 += s[2][k]*w; a3 += s[3][k]*w;
  }
  part[kq][0][jq]=a0; part[kq][1][jq]=a1; part[kq][2][jq]=a2; part[kq][3][jq]=a3;
  __syncthreads();
  if (kq == 0){
    float bb = (which ? bc : bx)[j];
    float* out = which ? mod_c : mod_x;
    #pragma unroll
    for (int b = 0; b < 4; ++b){
      out[(size_t)b*6912 + j] = part[0][b][jq] + part[1][b][jq] + part[2][b][jq] + part[3][b][jq] + bb;
    }
  }
}

// ---------------- fused LayerNorm + modulate (fp32 in, bf16 out) ----------------
__global__ __launch_bounds__(256) void ln_mod_kernel(
  const float* srcx, const float* srcc, const float* g, const float* bt,
  const float* gcn, const float* btc,
  const float* shx, const float* scx, const float* shc, const float* scc,
  u16* out)
{
  int m = blockIdx.x;
  bool isC = (m >= MX_);
  const float* src = isC ? srcc + (size_t)(m - MX_)*C_ : srcx + (size_t)m*C_;
  int bidx = isC ? ((m - MX_) >> 7) : (m >> 10);
  const float* gg = isC ? gcn : g;
  const float* bb = isC ? btc : bt;
  const float* sh = (isC ? shc : shx) + (size_t)bidx*6912;
  const float* sc = (isC ? scc : scx) + (size_t)bidx*6912;
  int tid = threadIdx.x;
  float lv[8];
  float sum = 0.f, sq = 0.f;
  if (tid < 144){
    float4 v0 = *(const float4*)(src + tid*8);
    float4 v1 = *(const float4*)(src + tid*8 + 4);
    lv[0]=v0.x; lv[1]=v0.y; lv[2]=v0.z; lv[3]=v0.w;
    lv[4]=v1.x; lv[5]=v1.y; lv[6]=v1.z; lv[7]=v1.w;
    #pragma unroll
    for (int j = 0; j < 8; ++j){ sum += lv[j]; sq += lv[j]*lv[j]; }
  }
  #pragma unroll
  for (int off = 1; off < 64; off <<= 1){ sum += __shfl_xor(sum, off); sq += __shfl_xor(sq, off); }
  __shared__ float rs[4], rq[4];
  int wave = tid >> 6, lane = tid & 63;
  if (lane == 0){ rs[wave] = sum; rq[wave] = sq; }
  __syncthreads();
  float S = rs[0]+rs[1]+rs[2]+rs[3];
  float Q = rq[0]+rq[1]+rq[2]+rq[3];
  float mean = S * (1.f/1152.f);
  float var  = Q * (1.f/1152.f) - mean*mean;
  float rstd = rsqrtf(var + 1e-6f);
  if (tid < 144){
    union { uint4 v; u16 s[8]; } o;
    #pragma unroll
    for (int j = 0; j < 8; ++j){
      int n = tid*8 + j;
      float val = (lv[j] - mean)*rstd*gg[n] + bb[n];
      val = val*(1.f + sc[n]) + sh[n];
      o.s[j] = f2b(val);
    }
    *(uint4*)(out + (size_t)m*C_ + tid*8) = o.v;
  }
}

// ---------------- split-K reduce: out = resid + gate*(p0+p1+bias) ----------------
__global__ __launch_bounds__(256) void reduce2_kernel(
  const float* p0, const float* p1,
  const float* residx, const float* residc,
  const float* modx, const float* modc,
  const float* biasx, const float* biasc,
  float* outx, float* outc)
{
  for (int i4 = blockIdx.x*256 + threadIdx.x; i4 < MT_*288; i4 += gridDim.x*256){
    int m = i4 / 288, n4 = (i4 % 288)*4;
    bool isC = (m >= MX_);
    int bidx = isC ? ((m - MX_) >> 7) : (m >> 10);
    const float* gate  = (isC ? modc : modx) + (size_t)bidx*6912;
    const float* bias  = isC ? biasc : biasx;
    const float* resid = isC ? residc + (size_t)(m - MX_)*C_ : residx + (size_t)m*C_;
    float* o = isC ? outc + (size_t)(m - MX_)*C_ : outx + (size_t)m*C_;
    float4 a = *(const float4*)(p0 + (size_t)m*C_ + n4);
    float4 b = *(const float4*)(p1 + (size_t)m*C_ + n4);
    float4 r = *(const float4*)(resid + n4);
    float4 ov;
    ov.x = r.x + gate[n4+0]*(a.x + b.x + bias[n4+0]);
    ov.y = r.y + gate[n4+1]*(a.y + b.y + bias[n4+1]);
    ov.z = r.z + gate[n4+2]*(a.z + b.z + bias[n4+2]);
    ov.w = r.w + gate[n4+3]*(a.w + b.w + bias[n4+3]);
    *(float4*)(o + n4) = ov;
  }
}

// ---------------- attn KV-split combine: O = (a1*w1 + a2*w2) / (l1*w1 + l2*w2) ----------------
__global__ __launch_bounds__(256) void attncomb_kernel(
  const u16* accP, const float* lP, const float* mP, u16* O)
{
  for (int i = blockIdx.x*256 + threadIdx.x; i < RWS_*18; i += gridDim.x*256){
    int row = i / 18, cg = i % 18;
    float m1 = mP[row], m2 = mP[RWS_ + row];
    float mm = fmaxf(m1, m2);
    float w1 = exp2f(m1 - mm), w2 = exp2f(m2 - mm);
    float rL = 1.f / (lP[row]*w1 + lP[RWS_ + row]*w2);
    const u16* a1 = accP + (size_t)row*80 + cg*4;
    const u16* a2 = accP + ((size_t)RWS_ + row)*80 + cg*4;
    union { uint2 v; u16 e[4]; } o;
    #pragma unroll
    for (int j = 0; j < 4; ++j)
      o.e[j] = f2b((b2f(a1[j])*w1 + b2f(a2[j])*w2) * rL);
    int b = row >> 14;              // row / (16*1152)
    int h = (row >> 10) & 15;       // hmm only valid if 1152 were 1024 -- compute properly below
    // recompute properly (1152 not a power of two):
    int bh = row / NT_;
    int tok = row - bh*NT_;
    b = bh >> 4; h = bh & 15;
    *(uint2*)(O + ((size_t)b*NT_ + tok)*C_ + h*D_ + cg*4) = o.v;
  }
}

// ---------------- GEMM: C = A @ B(^T stored), single-buffer 32KB, XCD-swizzled ----------------
struct GemmArgs {
  const u16* A; int lda; int rowmap;
  const u16* BTx; const u16* BTc;
  const float* biasx; const float* biasc;
  void* outx; void* outc;
  const float* residx; const float* residc;
  const float* gatex; const float* gatec;
  int N, K, kLen;
};

static __device__ __forceinline__ int amap(int m, int rowmap){
  if (rowmap){
    if (m < MX_) return (m >> 10)*NT_ + (m & 1023);
    int mm = m - MX_;
    return (mm >> 7)*NT_ + 1024 + (mm & 127);
  }
  return m;
}

template<int EPI>
__global__ __launch_bounds__(256, 2) void gemm_kernel(GemmArgs g){
  __shared__ u16 As[128*64];
  __shared__ u16 Bs[128*64];
  int gx = gridDim.x, gy = gridDim.y;
  int nwg = gx*gy;
  int orig = blockIdx.y*gx + blockIdx.x;
  int q = nwg >> 3, r8 = nwg & 7;
  int xcd = orig & 7, wi = orig >> 3;
  int swz = (xcd < r8 ? xcd*(q+1) : r8*(q+1) + (xcd - r8)*q) + wi;
  int n0 = (swz % gx)*128, m0 = (swz / gx)*128;
  int kStart = blockIdx.z * g.kLen;
  bool isC = (m0 >= MX_);
  const u16* BT = isC ? g.BTc : g.BTx;
  int tid = threadIdx.x, wave = tid >> 6, lane = tid & 63;
  int lg = lane >> 4, lr = lane & 15;
  int wm = wave >> 1, wn = wave & 1;
  f32x4 acc[4][4] = {};

  const u16* Aaddr[4]; const u16* Baddr[4];
  #pragma unroll
  for (int i = 0; i < 4; ++i){
    int cb = (wave*4 + i)*64;
    int qq = cb + lane;
    int row = qq >> 3;
    int c16 = (qq & 7) ^ (row & 7);
    Aaddr[i] = g.A + (size_t)amap(m0 + row, g.rowmap)*g.lda + kStart + c16*8;
    Baddr[i] = BT + (size_t)(n0 + row)*g.K + kStart + c16*8;
  }
  for (int k0 = 0; k0 < g.kLen; k0 += 64){
    #pragma unroll
    for (int i = 0; i < 4; ++i){
      int cb = (wave*4 + i)*64;
      gl_lds16(Aaddr[i] + k0, As + cb*8);
      gl_lds16(Baddr[i] + k0, Bs + cb*8);
    }
    __syncthreads();
    #pragma unroll
    for (int kkI = 0; kkI < 2; ++kkI){
      bf16x8 af[4], bfr[4];
      #pragma unroll
      for (int mi = 0; mi < 4; ++mi){
        int row = wm*64 + mi*16 + lr;
        int c16 = (kkI*4 + lg) ^ (row & 7);
        af[mi] = *(const bf16x8*)&As[row*64 + c16*8];
      }
      #pragma unroll
      for (int ni = 0; ni < 4; ++ni){
        int row = wn*64 + ni*16 + lr;
        int c16 = (kkI*4 + lg) ^ (row & 7);
        bfr[ni] = *(const bf16x8*)&Bs[row*64 + c16*8];
      }
      #pragma unroll
      for (int mi = 0; mi < 4; ++mi)
        #pragma unroll
        for (int ni = 0; ni < 4; ++ni)
          acc[mi][ni] = MFMA16(af[mi], bfr[ni], acc[mi][ni]);
    }
    __syncthreads();
  }

  const float* bias  = isC ? g.biasc : g.biasx;
  const float* resid = isC ? g.residc : g.residx;
  void* out = isC ? g.outc : g.outx;
  const float* gate = nullptr;
  if (EPI == 2){
    int bidx = isC ? ((m0 - MX_) >> 7) : (m0 >> 10);
    gate = (isC ? g.gatec : g.gatex) + (size_t)bidx*6912;
  }
  int mbase = isC ? (m0 - MX_) : m0;
  float* pbase = nullptr;
  if (EPI == 3) pbase = blockIdx.z ? (float*)g.outc : (float*)g.outx;
  #pragma unroll
  for (int mi = 0; mi < 4; ++mi){
    #pragma unroll
    for (int r = 0; r < 4; ++r){
      #pragma unroll
      for (int ni = 0; ni < 4; ++ni){
        int n = n0 + wn*64 + ni*16 + lr;
        if (EPI == 3){
          size_t prow = (size_t)(m0 + wm*64 + mi*16 + lg*4 + r);
          pbase[prow*(size_t)g.N + n] = acc[mi][ni][r];
        } else {
          size_t orow = (size_t)(mbase + wm*64 + mi*16 + lg*4 + r);
          float v = acc[mi][ni][r] + bias[n];
          if (EPI == 1){
            float u = 0.7978845608028654f*(v + 0.044715f*v*v*v);
            v = 0.5f*v*(1.f + tanhf(u));
          }
          if (EPI == 2){
            v = resid[orow*(size_t)g.N + n] + gate[n]*v;
            ((float*)out)[orow*(size_t)g.N + n] = v;
          } else {
            ((u16*)out)[orow*(size_t)g.N + n] = f2b(v);
          }
        }
      }
    }
  }
}

// ---------------- head split + RMS-norm(q,k) + pad + V transpose ----------------
__global__ __launch_bounds__(256) void rmshead_kernel(
  const u16* qkv, const float* gqx, const float* gkx, const float* gqc, const float* gkc,
  u16* qpad, u16* kpad, u16* vT)
{
  int tt = blockIdx.x, h = blockIdx.y, b = blockIdx.z;
  int t0 = tt*64;
  bool isC = (t0 >= 1024);
  size_t rowbase = isC ? (size_t)(MX_ + b*128 + (t0 - 1024)) : (size_t)(b*1024 + t0);
  __shared__ u16 sq[2][64][72];
  __shared__ u16 sv[64][72];
  __shared__ float nf[2][64];
  int tid = threadIdx.x;
  for (int s = tid; s < 1728; s += 256){
    int which = s / 576, rem = s % 576;
    int t = rem / 9, ch = rem % 9;
    uint4 v = *(const uint4*)(qkv + (rowbase + t)*3456 + which*C_ + h*D_ + ch*8);
    u16* dst = (which < 2) ? &sq[which][t][ch*8] : &sv[t][ch*8];
    *(uint4*)dst = v;
  }
  __syncthreads();
  {
    int row = tid >> 1, half = tid & 1;
    int which = row >> 6, t = row & 63;
    float ss = 0.f;
    for (int d = half*36; d < half*36 + 36; ++d){
      float v = b2f(sq[which][t][d]); ss += v*v;
    }
    ss += __shfl_xor(ss, 1);
    if (half == 0){
      const float* gp = (which == 0) ? (isC ? gqc : gqx) : (isC ? gkc : gkx);
      float f = 33.9411254970f * gp[0] / fmaxf(sqrtf(ss), 1e-12f);
      if (which == 0) f *= 0.17002324581205f;   // ATTN_SCALE * log2(e) folded into q
      nf[which][t] = f;
    }
  }
  __syncthreads();
  size_t obase = ((size_t)(b*H_ + h)*NT_ + t0) * DP_;
  for (int s = tid; s < 1536; s += 256){
    int which = s / 768, rem = s % 768;
    int t = rem / 12, ch = rem % 12;
    float f = nf[which][t];
    union { uint4 v; u16 e[8]; } o;
    #pragma unroll
    for (int j = 0; j < 8; ++j){
      int d = ch*8 + j;
      o.e[j] = (d < D_) ? f2b(b2f(sq[which][t][d]) * f) : (u16)0;
    }
    *(uint4*)((which == 0 ? qpad : kpad) + obase + (size_t)t*DP_ + ch*8) = o.v;
  }
  size_t vbase = (size_t)(b*H_ + h)*80*NT_;
  for (int s = tid; s < 576; s += 256){
    int d = s / 8, ch = s % 8;
    union { uint4 v; u16 e[8]; } o;
    #pragma unroll
    for (int j = 0; j < 8; ++j) o.e[j] = sv[ch*8 + j][d];
    *(uint4*)(vT + vbase + (size_t)d*NT_ + t0 + ch*8) = o.v;
  }
  for (int s = tid; s < 512; s += 256){
    int d = 72 + (s >> 6), t = s & 63;
    vT[vbase + (size_t)d*NT_ + t0 + t] = (d == 72) ? (u16)0x3F80 : (u16)0;
  }
}

// ---------------- attention: KV-split x2, 32 q-rows/wave, XCD-chunked, barrier-free ----------------
// Grid 1152 = 8 XCDs x 144; w=(orig&7)*144+(orig>>3); head = w/18 (8 heads/XCD, L2-resident
// K/V), sub = w%18: qtb = sub>>1, kv-half = sub&1 (18 of 36 KV tiles each). Identical TILE
// body and register footprint as the proven R10 kernel (compiles 120 VGPR) but HALF the
// work per wave and ~4 waves/SIMD resident -> stall overlap. Writes unnormalized partials
// (acc bf16 stride-80 + l,m fp32); attncomb merges the two halves.
__global__ __launch_bounds__(256) __attribute__((amdgpu_waves_per_eu(1, 2))) void attn_kernel(
  const u16* qpad, const u16* kpad, const u16* vT,
  u16* accP, float* lP, float* mP)
{
  __shared__ u16 Ps[4][32][40];
  int orig = blockIdx.x;
  int w = (orig & 7)*144 + (orig >> 3);
  int sub = w % 18, hb = w / 18;
  int qtb = sub >> 1, half = sub & 1;
  int h = hb & 15, b = hb >> 4;
  int bh = b*H_ + h;
  int tid = threadIdx.x, wave = tid >> 6, lane = tid & 63;
  int lg = lane >> 4, lr = lane & 15;
  int q0 = qtb*128 + wave*32;
  int tbase = half*18;

  const u16* qb = qpad + (size_t)bh*NT_*DP_;
  const u16* kb = kpad + (size_t)bh*NT_*DP_;
  const u16* vb = vT + (size_t)bh*80*NT_;

  bf16x8 qf[2][3];
  #pragma unroll
  for (int qt = 0; qt < 2; ++qt)
    #pragma unroll
    for (int kk = 0; kk < 3; ++kk)
      qf[qt][kk] = *(const bf16x8*)(qb + (size_t)(q0 + qt*16 + lr)*DP_ + kk*32 + lg*8);

  f32x4 acc[5][2] = {};
  float m0 = -1e30f, m1 = -1e30f;

  bf16x8 kfA[2][3], kfB[2][3], vf[5];
  auto LOADK = [&](bf16x8 (&kf)[2][3], int kvt){
    #pragma unroll
    for (int kt = 0; kt < 2; ++kt)
      #pragma unroll
      for (int kk = 0; kk < 3; ++kk)
        kf[kt][kk] = *(const bf16x8*)(kb + (size_t)(kvt*32 + kt*16 + lr)*DP_ + kk*32 + lg*8);
  };
  u16* prow0 = &Ps[wave][lr][0];
  u16* prow1 = &Ps[wave][16 + lr][0];

  auto TILE = [&](bf16x8 (&kf)[2][3], bf16x8 (&kfn)[2][3], int t){
    #pragma unroll
    for (int dc = 0; dc < 5; ++dc)
      vf[dc] = *(const bf16x8*)(vb + (size_t)(dc*16 + lr)*NT_ + t*32 + lg*8);
    if (t + 1 < tbase + 18) LOADK(kfn, t + 1);

    f32x4 st[2][2] = {};
    __builtin_amdgcn_s_setprio(1);
    #pragma unroll
    for (int kk = 0; kk < 3; ++kk){
      st[0][0] = MFMA16(kf[0][kk], qf[0][kk], st[0][0]);
      st[0][1] = MFMA16(kf[0][kk], qf[1][kk], st[0][1]);
      st[1][0] = MFMA16(kf[1][kk], qf[0][kk], st[1][0]);
      st[1][1] = MFMA16(kf[1][kk], qf[1][kk], st[1][1]);
    }
    __builtin_amdgcn_s_setprio(0);

    float pm0 = fmaxf(fmaxf(fmaxf(st[0][0][0], st[0][0][1]), fmaxf(st[0][0][2], st[0][0][3])),
                      fmaxf(fmaxf(st[1][0][0], st[1][0][1]), fmaxf(st[1][0][2], st[1][0][3])));
    float pm1 = fmaxf(fmaxf(fmaxf(st[0][1][0], st[0][1][1]), fmaxf(st[0][1][2], st[0][1][3])),
                      fmaxf(fmaxf(st[1][1][0], st[1][1][1]), fmaxf(st[1][1][2], st[1][1][3])));
    float tt = fmaxf(pm0 - m0, pm1 - m1);
    if (!__all(tt <= 11.5415603f)){
      float r0 = fmaxf(pm0, __shfl_xor(pm0, 16)); r0 = fmaxf(r0, __shfl_xor(r0, 32));
      float r1 = fmaxf(pm1, __shfl_xor(pm1, 16)); r1 = fmaxf(r1, __shfl_xor(r1, 32));
      float n0 = fmaxf(m0, r0), n1 = fmaxf(m1, r1);
      float f0 = exp2f(m0 - n0), f1 = exp2f(m1 - n1);
      m0 = n0; m1 = n1;
      #pragma unroll
      for (int dc = 0; dc < 5; ++dc)
        #pragma unroll
        for (int j = 0; j < 4; ++j){ acc[dc][0][j] *= f0; acc[dc][1][j] *= f1; }
    }
    #pragma unroll
    for (int kt = 0; kt < 2; ++kt){
      #pragma unroll
      for (int qt = 0; qt < 2; ++qt){
        float mm = qt ? m1 : m0;
        float e0 = exp2f(st[kt][qt][0] - mm);
        float e1 = exp2f(st[kt][qt][1] - mm);
        float e2 = exp2f(st[kt][qt][2] - mm);
        float e3 = exp2f(st[kt][qt][3] - mm);
        u32 lo, hi;
        asm("v_cvt_pk_bf16_f32 %0, %1, %2" : "=v"(lo) : "v"(e0), "v"(e1));
        asm("v_cvt_pk_bf16_f32 %0, %1, %2" : "=v"(hi) : "v"(e2), "v"(e3));
        uint2 pkd; pkd.x = lo; pkd.y = hi;
        *(uint2*)((qt ? prow1 : prow0) + kt*16 + lg*4) = pkd;
      }
    }
    asm volatile("s_waitcnt lgkmcnt(0)" ::: "memory");
    __builtin_amdgcn_sched_barrier(0);
    bf16x8 bp0 = *(const bf16x8*)(prow0 + lg*8);
    bf16x8 bp1 = *(const bf16x8*)(prow1 + lg*8);
    __builtin_amdgcn_s_setprio(1);
    #pragma unroll
    for (int dc = 0; dc < 5; ++dc){
      acc[dc][0] = MFMA16(vf[dc], bp0, acc[dc][0]);
      acc[dc][1] = MFMA16(vf[dc], bp1, acc[dc][1]);
    }
    __builtin_amdgcn_s_setprio(0);
  };

  LOADK(kfA, tbase);
  for (int t2 = 0; t2 < 9; ++t2){
    TILE(kfA, kfB, tbase + 2*t2);
    TILE(kfB, kfA, tbase + 2*t2 + 1);
  }

  // write unnormalized partials: acc (bf16, stride 80) + l,m (fp32)
  #pragma unroll
  for (int qt = 0; qt < 2; ++qt){
    size_t row = (size_t)half*RWS_ + (size_t)bh*NT_ + (q0 + qt*16 + lr);
    u16* arow = accP + row*80;
    #pragma unroll
    for (int dc = 0; dc < 5; ++dc){
      union { uint2 v; u16 e[4]; } o;
      #pragma unroll
      for (int j = 0; j < 4; ++j) o.e[j] = f2b(acc[dc][qt][j]);
      *(uint2*)(arow + dc*16 + lg*4) = o.v;
    }
    if (lg == 2) lP[row] = acc[4][qt][0];     // col 72 = ones-row sum l
    if (lg == 0) mP[row] = qt ? m1 : m0;      // m uniform across lg
  }
}

// ---------------- host ----------------
extern "C" void kernel_launch(void* const* d_in, const int* in_sizes, int n_in,
                              void* d_out, int out_size, void* d_ws, size_t ws_size,
                              hipStream_t stream)
{
  (void)in_sizes; (void)n_in; (void)out_size; (void)ws_size;
  const float* x        = (const float*)d_in[0];
  const float* c        = (const float*)d_in[1];
  const float* gc       = (const float*)d_in[2];
  const float* ada_x_w  = (const float*)d_in[3];
  const float* ada_x_b  = (const float*)d_in[4];
  const float* ada_c_w  = (const float*)d_in[5];
  const float* ada_c_b  = (const float*)d_in[6];
  const float* g1x_g    = (const float*)d_in[7];
  const float* g1x_b    = (const float*)d_in[8];
  const float* g2x_g    = (const float*)d_in[9];
  const float* g2x_b    = (const float*)d_in[10];
  const float* g1c_g    = (const float*)d_in[11];
  const float* g1c_b    = (const float*)d_in[12];
  const float* g2c_g    = (const float*)d_in[13];
  const float* g2c_b    = (const float*)d_in[14];
  const float* qkv_x_w  = (const float*)d_in[15];
  const float* qkv_x_b  = (const float*)d_in[16];
  const float* proj_x_w = (const float*)d_in[17];
  const float* proj_x_b = (const float*)d_in[18];
  const float* qkv_c_w  = (const float*)d_in[19];
  const float* qkv_c_b  = (const float*)d_in[20];
  const float* proj_c_w = (const float*)d_in[21];
  const float* proj_c_b = (const float*)d_in[22];
  const float* gq_x     = (const float*)d_in[23];
  const float* gk_x     = (const float*)d_in[24];
  const float* gq_c     = (const float*)d_in[25];
  const float* gk_c     = (const float*)d_in[26];
  const float* m_x_w1   = (const float*)d_in[27];
  const float* m_x_b1   = (const float*)d_in[28];
  const float* m_x_w2   = (const float*)d_in[29];
  const float* m_x_b2   = (const float*)d_in[30];
  const float* m_c_w1   = (const float*)d_in[31];
  const float* m_c_b1   = (const float*)d_in[32];
  const float* m_c_w2   = (const float*)d_in[33];
  const float* m_c_b2   = (const float*)d_in[34];
  float* out = (float*)d_out;

  char* ws = (char*)d_ws;
  size_t off = 0;
  auto alloc = [&](size_t bytes)->void*{ void* p = ws + off; off += (bytes + 255) & ~(size_t)255; return p; };
  u16* WTqx  = (u16*)alloc((size_t)3456*1152*2);
  u16* WTqc  = (u16*)alloc((size_t)3456*1152*2);
  u16* WTpx  = (u16*)alloc((size_t)1152*1152*2);
  u16* WTpc  = (u16*)alloc((size_t)1152*1152*2);
  u16* WTm1x = (u16*)alloc((size_t)4608*1152*2);
  u16* WTm2x = (u16*)alloc((size_t)1152*4608*2);
  u16* WTm1c = (u16*)alloc((size_t)4608*1152*2);
  u16* WTm2c = (u16*)alloc((size_t)1152*4608*2);
  float* mod_x = (float*)alloc((size_t)4*6912*4);
  float* mod_c = (float*)alloc((size_t)4*6912*4);
  u16* xin  = (u16*)alloc((size_t)4608*1152*2);
  u16* pool = (u16*)alloc((size_t)4608*4608*2);     // qkv out; later attn partials; later MLP hidden
  u16* qpad = (u16*)alloc((size_t)64*1152*96*2 + 4096);
  u16* kpad = (u16*)alloc((size_t)64*1152*96*2 + 4096);
  u16* vTb  = (u16*)alloc((size_t)64*80*1152*2 + 4096);
  u16* Obuf = (u16*)alloc((size_t)4*1152*1152*2);
  float* x1c1 = (float*)alloc((size_t)4608*1152*4);
  // attn partials live in pool (dead between rmshead and fc1): acc 2x73728x80 bf16 = 23.6MB,
  // l/m 2x73728 f32 = 1.2MB; total 24.8MB <= pool 42.5MB
  u16* accP = pool;
  float* lP = (float*)(pool + (size_t)2*RWS_*80);
  float* mP = lP + (size_t)2*RWS_;
  // split-K partial buffers (dead spans, as R12/R13)
  float* fc2p0 = (float*)qpad;
  float* fc2p1 = fc2p0 + (size_t)MT_*C_;
  float* projp0 = (float*)qpad;

  // L0: weight transposes (fp32 -> bf16 [N][K])
  {
    TrArgs ta;
    const float* srcs[8] = {qkv_x_w, qkv_c_w, proj_x_w, proj_c_w, m_x_w1, m_x_w2, m_c_w1, m_c_w2};
    u16* dsts[8]         = {WTqx, WTqc, WTpx, WTpc, WTm1x, WTm2x, WTm1c, WTm2c};
    int Ks[8] = {1152,1152,1152,1152,1152,4608,1152,4608};
    int Ns[8] = {3456,3456,1152,1152,4608,1152,4608,1152};
    int st = 0;
    for (int i = 0; i < 8; ++i){
      ta.src[i] = srcs[i]; ta.dst[i] = dsts[i]; ta.K[i] = Ks[i]; ta.N[i] = Ns[i];
      ta.start[i] = st; st += (Ks[i]/32)*(Ns[i]/32);
    }
    ta.start[8] = st;
    transpose_kernel<<<dim3(st), dim3(256), 0, stream>>>(ta);
  }
  // L1: adaLN modulation vectors
  ada_kernel<<<dim3(216), dim3(256), 0, stream>>>(gc, ada_x_w, ada_x_b, ada_c_w, ada_c_b, mod_x, mod_c);
  // L2: LN1 + modulate
  ln_mod_kernel<<<dim3(4608), dim3(256), 0, stream>>>(
      x, c, g1x_g, g1x_b, g1c_g, g1c_b,
      mod_x + 0, mod_x + 1152, mod_c + 0, mod_c + 1152, xin);
  // L3: qkv GEMM (merged x|c)
  {
    GemmArgs ga{};
    ga.A = xin; ga.lda = 1152; ga.rowmap = 0;
    ga.BTx = WTqx; ga.BTc = WTqc; ga.biasx = qkv_x_b; ga.biasc = qkv_c_b;
    ga.outx = pool; ga.outc = pool + (size_t)4096*3456;
    ga.N = 3456; ga.K = 1152; ga.kLen = 1152;
    gemm_kernel<0><<<dim3(27,36), dim3(256), 0, stream>>>(ga);
  }
  // L4: head split + RMS + pad + V^T
  rmshead_kernel<<<dim3(18,16,4), dim3(256), 0, stream>>>(pool, gq_x, gk_x, gq_c, gk_c, qpad, kpad, vTb);
  // L5a: attention KV-split x2 -> partials (pool is dead now; qkv data fully consumed by L4)
  attn_kernel<<<dim3(1152), dim3(256), 0, stream>>>(qpad, kpad, vTb, accP, lP, mP);
  // L5b: combine halves -> Obuf
  attncomb_kernel<<<dim3(2048), dim3(256), 0, stream>>>(accP, lP, mP, Obuf);
  // L6a: proj split-K=2 -> raw fp32 partials
  {
    GemmArgs ga{};
    ga.A = Obuf; ga.lda = 1152; ga.rowmap = 1;
    ga.BTx = WTpx; ga.BTc = WTpc;
    ga.outx = projp0; ga.outc = x1c1;
    ga.N = 1152; ga.K = 1152; ga.kLen = 576;
    gemm_kernel<3><<<dim3(9,36,2), dim3(256), 0, stream>>>(ga);
  }
  // L6b: reduce partials + bias + gate + residual -> x1c1 (p1 aliases out; elementwise safe)
  reduce2_kernel<<<dim3(2048), dim3(256), 0, stream>>>(
      projp0, x1c1, x, c,
      mod_x + 2*1152, mod_c + 2*1152, proj_x_b, proj_c_b,
      x1c1, x1c1 + (size_t)4096*1152);
  // L7: LN2 + modulate (reads fp32 x1c1)
  ln_mod_kernel<<<dim3(4608), dim3(256), 0, stream>>>(
      x1c1, x1c1 + (size_t)4096*1152, g2x_g, g2x_b, g2c_g, g2c_b,
      mod_x + 3*1152, mod_x + 4*1152, mod_c + 3*1152, mod_c + 4*1152, xin);
  // L8: MLP fc1 + GELU
  {
    GemmArgs ga{};
    ga.A = xin; ga.lda = 1152; ga.rowmap = 0;
    ga.BTx = WTm1x; ga.BTc = WTm1c; ga.biasx = m_x_b1; ga.biasc = m_c_b1;
    ga.outx = pool; ga.outc = pool + (size_t)4096*4608;
    ga.N = 4608; ga.K = 1152; ga.kLen = 1152;
    gemm_kernel<1><<<dim3(36,36), dim3(256), 0, stream>>>(ga);
  }
  // L9a: MLP fc2 split-K=2 -> raw fp32 partials (no atomics)
  {
    GemmArgs ga{};
    ga.A = pool; ga.lda = 4608; ga.rowmap = 0;
    ga.BTx = WTm2x; ga.BTc = WTm2c;
    ga.outx = fc2p0; ga.outc = fc2p1;
    ga.N = 1152; ga.K = 4608; ga.kLen = 2304;
    gemm_kernel<3><<<dim3(9,36,2), dim3(256), 0, stream>>>(ga);
  }
  // L9b: reduce partials + bias + gate + residual -> d_out
  reduce2_kernel<<<dim3(2048), dim3(256), 0, stream>>>(
      fc2p0, fc2p1, x1c1, x1c1 + (size_t)4096*1152,
      mod_x + 5*1152, mod_c + 5*1152, m_x_b2, m_c_b2,
      out, out + (size_t)4096*1152);
}